// Round 12
// baseline (298.554 us; speedup 1.0000x reference)
//
#include <hip/hip_runtime.h>
#include <cstdint>
#include <cstddef>

// ---------------------------------------------------------------------------
// Block_85375359910651: RPE-attention transformer block on gfx950.
// B=32 T=500 C=512 H=8 D=64, buckets=49. bf16 MFMA pipeline (threshold 0.106).
// rpe[b,h,t,s] == rpe_table[b//4, bucket[8*(b%4)+h, t, s]]
// R15: FC1 GEMM retiled. R14 profile: gemm_bt<128,1> (FC1) = 78us top kernel
//   (2 blocks/CU, MfmaUtil 8%, all pipes idle); structurally identical FC2
//   (gemm_bt<64,3>, 4 blocks/CU) not even in top-5. -> FC1 switched to
//   gemm_bt<64,1>: 2048 blocks of 128x64, 4 blocks/CU (the proven config).
//   A re-reads 2x but FETCH=12MB shows L3 absorbs. Avoids R13's
//   launch_bounds(256,3) compile-hang route entirely.
//   Everything else identical to R14 (= R9 verbatim, 283.7us verified).
// ---------------------------------------------------------------------------

typedef unsigned short ushort_t;
typedef __bf16 bf16x8 __attribute__((ext_vector_type(8)));
typedef float floatx4 __attribute__((ext_vector_type(4)));
typedef unsigned short ushort4v __attribute__((ext_vector_type(4)));
typedef unsigned short ushort8v __attribute__((ext_vector_type(8)));

#define DEV __device__ __forceinline__

#define B_ 32
#define T_ 500
#define C_ 512
#define H_ 8
#define M_ 16000      // B*T

// ---- workspace layout (bytes), total ~94.7 MB ----
#define OFF_QK     0ULL            // 16016*1024*2 = 32,800,768  (later: h 16000*1024*2)
#define OFF_XBF    32800768ULL     // 16,384,000                 (later: x1)
#define OFF_BUCKET 49184768ULL     // 8,192,000   u8 (32,500,512) permuted
#define OFF_VT     57376768ULL     // 16,777,216  bf16 (32,8,64,512)
#define OFF_Y      74153984ULL     // 16,384,000  bf16 attn out
#define OFF_WATTN  90537984ULL     // 1,572,864   bf16 (1536,512)
#define OFF_WPROJ  92110848ULL     // 524,288     bf16 (512,512)
#define OFF_WFC    92635136ULL     // 1,048,576   bf16 (1024,512)
#define OFF_WFC2   93683712ULL     // 1,048,576   bf16 (512,1024)
#define VT_BYTES   16777216ULL

DEV ushort_t f2bf(float f) {
  union { float f; unsigned u; } v; v.f = f;
  unsigned r = v.u + 0x7fffu + ((v.u >> 16) & 1u);   // RNE
  return (ushort_t)(r >> 16);
}
DEV float bf2f(ushort_t u) {
  union { unsigned u; float f; } v; v.u = ((unsigned)u) << 16;
  return v.f;
}

DEV void gload16(const void* g, void* l) {
  __builtin_amdgcn_global_load_lds(
      (__attribute__((address_space(1))) void*)(g),
      (__attribute__((address_space(3))) void*)(l), 16, 0, 0);
}

// ---------------------------------------------------------------------------
__global__ __launch_bounds__(256) void cvt_bf16(const float* __restrict__ in,
                                                ushort_t* __restrict__ out, int n) {
  int i = (blockIdx.x * 256 + threadIdx.x) * 4;
  if (i >= n) return;
  float4 v = *(const float4*)(in + i);
  ushort4v o = { f2bf(v.x), f2bf(v.y), f2bf(v.z), f2bf(v.w) };
  *(ushort4v*)(out + i) = o;
}

// ---------------------------------------------------------------------------
// All four weight transposes in one launch. (K,N) fp32 -> (N,K) bf16.
// ---------------------------------------------------------------------------
struct WTDesc { const float* w; ushort_t* wt; int K; int N; };
struct WTArgs { WTDesc d[4]; };

__global__ __launch_bounds__(256) void wtrans_all(WTArgs a) {
  const int bid = blockIdx.x;
  int z, local;
  if (bid < 768)       { z = 0; local = bid; }
  else if (bid < 1024) { z = 1; local = bid - 768; }
  else if (bid < 1536) { z = 2; local = bid - 1024; }
  else                 { z = 3; local = bid - 1536; }
  const WTDesc dd = a.d[z];
  const int gx = dd.N >> 5;
  const int n0 = (local % gx) * 32, k0 = (local / gx) * 32;

  __shared__ float tile[32][33];
  const int c = threadIdx.x & 31, r = threadIdx.x >> 5;
#pragma unroll
  for (int rr = 0; rr < 4; ++rr)
    tile[r + rr * 8][c] = dd.w[(size_t)(k0 + r + rr * 8) * dd.N + n0 + c];
  __syncthreads();
#pragma unroll
  for (int rr = 0; rr < 4; ++rr)
    dd.wt[(size_t)(n0 + r + rr * 8) * dd.K + k0 + c] = f2bf(tile[c][r + rr * 8]);
}

// ---------------------------------------------------------------------------
// bucket ids, PERMUTED layout: row stride 512; within 64-col block, byte at
// (s&15)*4 + ((s>>4)&3) holds column s. Byte value PRE-SCALED x4 (bpermute
// byte address). Consumer (swapped-QK layout) reads one uint4 at quad*16:
// byte (r*4+tn) = s = tn*16+quad*4+r  -> 16 needed bytes are contiguous.
// grid (125, 32): ct row staged in LDS, wave w handles t = bx*4 + w.
// ---------------------------------------------------------------------------
__global__ __launch_bounds__(256) void bucket_kernel(const int* __restrict__ ct,
                                                     unsigned char* __restrict__ bucket) {
  const int b = blockIdx.y;
  const int tid = threadIdx.x, w = tid >> 6, lane = tid & 63;
  __shared__ int2 ctS[500];
  for (int j = tid; j < T_; j += 256) ctS[j] = ((const int2*)ct)[(size_t)b * T_ + j];
  __syncthreads();
  const int t = blockIdx.x * 4 + w;
  const int2 a = ctS[t];
  const float ax = (float)a.x, ay = (float)a.y;
  const size_t rowbase = (size_t)(b * T_ + t) << 9;
#pragma unroll
  for (int it = 0; it < 8; ++it) {
    const int s = it * 64 + lane;
    if (s < T_) {
      const int2 c2 = ctS[s];
      const float dx = ax - (float)c2.x, dy = ay - (float)c2.y;
      const float dist = __builtin_amdgcn_sqrtf(dx * dx + dy * dy);
      const float rel = truncf(dist * (1.0f / 12.0f));
      const float far = fminf(
          rintf(fmaf(__builtin_amdgcn_logf(rel * (1.0f / 12.0f)), 4.0f, 12.0f)), 24.0f);
      const float idx = (rel <= 12.0f) ? rel : far;
      bucket[rowbase + (s >> 6) * 64 + (s & 15) * 4 + ((s >> 4) & 3)]
          = (unsigned char)(((int)idx + 24) << 2);   // pre-scaled byte addr
    }
  }
}

// ---------------------------------------------------------------------------
// qkv GEMM with fused V-transpose epilogue. A(M x 512) * Wt(1536 x 512)^T.
// Flat grid 1536 = 8 xcd * 16 mg * 12 n, XCD-swizzled.
// ---------------------------------------------------------------------------
__global__ __launch_bounds__(256, 2)
void gemm_qkv(const ushort_t* __restrict__ A,
              const ushort_t* __restrict__ Bt,
              const float* __restrict__ bias,
              ushort_t* __restrict__ qk,
              ushort_t* __restrict__ vt) {
  constexpr int K = 512;
  const int bid = blockIdx.x;
  const int xcd = bid & 7, k = bid >> 3;
  const int n_blk = k % 12, mg = k / 12;
  const int m_blk = mg * 8 + xcd;
  if (m_blk >= 125) return;
  const int m0 = m_blk * 128, n0 = n_blk * 128;

  __shared__ __align__(16) ushort_t As[128 * 64];
  __shared__ __align__(16) ushort_t Bs[128 * 64];
  const int tid = threadIdx.x;
  const int lane = tid & 63, w = tid >> 6;
  const int wm = w >> 1, wn = w & 1;
  const int quad = lane >> 4, l15 = lane & 15;

  floatx4 acc[4][4] = {};

  for (int k0 = 0; k0 < K; k0 += 64) {
    __syncthreads();
#pragma unroll
    for (int j = 0; j < 4; ++j) {
      const int chunk = j * 256 + tid;
      const int row = chunk >> 3, pos = chunk & 7, c = pos ^ (row & 7);
      gload16(A + (size_t)(m0 + row) * K + k0 + c * 8, (char*)As + j * 4096 + w * 1024);
      gload16(Bt + (size_t)(n0 + row) * K + k0 + c * 8, (char*)Bs + j * 4096 + w * 1024);
    }
    asm volatile("s_waitcnt vmcnt(0)" ::: "memory");
    __syncthreads();

#pragma unroll
    for (int kq = 0; kq < 2; ++kq) {
      bf16x8 af[4], bfr[4];
#pragma unroll
      for (int t = 0; t < 4; ++t) {
        const int rowa = wm * 64 + t * 16 + l15;
        const int posa = (kq * 4 + quad) ^ (rowa & 7);
        af[t] = *(const bf16x8*)((const char*)As + rowa * 128 + posa * 16);
        const int rowb = wn * 64 + t * 16 + l15;
        const int posb = (kq * 4 + quad) ^ (rowb & 7);
        bfr[t] = *(const bf16x8*)((const char*)Bs + rowb * 128 + posb * 16);
      }
#pragma unroll
      for (int tm = 0; tm < 4; ++tm)
#pragma unroll
        for (int tn = 0; tn < 4; ++tn)
          acc[tm][tn] = __builtin_amdgcn_mfma_f32_16x16x32_bf16(af[tm], bfr[tn], acc[tm][tn], 0, 0, 0);
    }
  }

  if (n0 < 1024) {   // Q,K path (uniform per block)
#pragma unroll
    for (int tn = 0; tn < 4; ++tn) {
      const int n = n0 + wn * 64 + tn * 16 + l15;
      const float bs = bias[n];
#pragma unroll
      for (int tm = 0; tm < 4; ++tm)
#pragma unroll
        for (int r = 0; r < 4; ++r) {
          const int m = m0 + wm * 64 + tm * 16 + quad * 4 + r;
          qk[(size_t)m * 1024 + n] = f2bf(acc[tm][tn][r] + bs);
        }
    }
  } else {           // V path: transpose into vt
#pragma unroll
    for (int tn = 0; tn < 4; ++tn) {
      const int n = n0 + wn * 64 + tn * 16 + l15;
      const float bs = bias[n];
      const int hh = (n >> 6) - 16, dd = n & 63;
#pragma unroll
      for (int tm = 0; tm < 4; ++tm) {
        const int mb = m0 + wm * 64 + tm * 16 + quad * 4;
        const int bb = mb / 500;
        const int ss = mb - bb * 500;
        ushort4v pk;
#pragma unroll
        for (int r = 0; r < 4; ++r) pk[r] = f2bf(acc[tm][tn][r] + bs);
        *(ushort4v*)(vt + (((size_t)(bb * 8 + hh)) * 64 + dd) * 512 + ss) = pk;
      }
    }
  }
}

// ---------------------------------------------------------------------------
// GEMM: C(M x N) = A(M x K) * Bt(N x K)^T.  128 x TN tile, BK=64, XCD swizzle.
// Flat grid 8 * 16 * (N/TN). EPI 1: bf16(gelu)  2: f32(+resf)  3: f32(+resb)
// ---------------------------------------------------------------------------
template <int TN, int EPI>
__global__ __launch_bounds__(256, TN == 64 ? 4 : 2)
void gemm_bt(const ushort_t* __restrict__ A,
             const ushort_t* __restrict__ Bt,
             const float* __restrict__ bias,
             const float* __restrict__ resf,
             const ushort_t* __restrict__ resb,
             void* __restrict__ outp,
             int N, int K) {
  constexpr int TMW = (TN == 128) ? 4 : 2;
  const int nn = N / TN;
  const int bid = blockIdx.x;
  const int xcd = bid & 7, kk = bid >> 3;
  const int n_blk = kk % nn, mg = kk / nn;
  const int m_blk = mg * 8 + xcd;
  if (m_blk >= 125) return;
  const int m0 = m_blk * 128, n0 = n_blk * TN;

  __shared__ __align__(16) ushort_t As[128 * 64];
  __shared__ __align__(16) ushort_t Bs[TN * 64];
  const int tid = threadIdx.x;
  const int lane = tid & 63, w = tid >> 6;
  const int wm = (TN == 128) ? (w >> 1) : w;
  const int wn = (TN == 128) ? (w & 1) : 0;
  const int quad = lane >> 4, l15 = lane & 15;

  floatx4 acc[TMW][4] = {};

  for (int k0 = 0; k0 < K; k0 += 64) {
    __syncthreads();
#pragma unroll
    for (int j = 0; j < 4; ++j) {
      const int chunk = j * 256 + tid;
      const int row = chunk >> 3, pos = chunk & 7, c = pos ^ (row & 7);
      gload16(A + (size_t)(m0 + row) * K + k0 + c * 8, (char*)As + j * 4096 + w * 1024);
    }
#pragma unroll
    for (int j = 0; j < TN / 32; ++j) {
      const int chunk = j * 256 + tid;
      const int row = chunk >> 3, pos = chunk & 7, c = pos ^ (row & 7);
      gload16(Bt + (size_t)(n0 + row) * K + k0 + c * 8, (char*)Bs + j * 4096 + w * 1024);
    }
    asm volatile("s_waitcnt vmcnt(0)" ::: "memory");
    __syncthreads();

#pragma unroll
    for (int kq = 0; kq < 2; ++kq) {
      bf16x8 af[TMW], bfr[4];
#pragma unroll
      for (int t = 0; t < TMW; ++t) {
        const int row = wm * (TMW * 16) + t * 16 + l15;
        const int pos = (kq * 4 + quad) ^ (row & 7);
        af[t] = *(const bf16x8*)((const char*)As + row * 128 + pos * 16);
      }
#pragma unroll
      for (int t = 0; t < 4; ++t) {
        const int row = wn * 64 + t * 16 + l15;
        const int pos = (kq * 4 + quad) ^ (row & 7);
        bfr[t] = *(const bf16x8*)((const char*)Bs + row * 128 + pos * 16);
      }
#pragma unroll
      for (int tm = 0; tm < TMW; ++tm)
#pragma unroll
        for (int tn = 0; tn < 4; ++tn)
          acc[tm][tn] = __builtin_amdgcn_mfma_f32_16x16x32_bf16(af[tm], bfr[tn], acc[tm][tn], 0, 0, 0);
    }
  }

#pragma unroll
  for (int tn = 0; tn < 4; ++tn) {
    const int n = n0 + wn * 64 + tn * 16 + l15;
    const float bs = bias[n];
#pragma unroll
    for (int tm = 0; tm < TMW; ++tm) {
#pragma unroll
      for (int r = 0; r < 4; ++r) {
        const int m = m0 + wm * (TMW * 16) + tm * 16 + quad * 4 + r;
        const float v = acc[tm][tn][r] + bs;
        if (EPI == 1) {
          const float gv = 0.5f * v * (1.0f + erff(v * 0.70710678118654752f));
          ((ushort_t*)outp)[(size_t)m * N + n] = f2bf(gv);
        } else if (EPI == 2) {
          ((float*)outp)[(size_t)m * N + n] = v + resf[(size_t)m * N + n];
        } else {
          ((float*)outp)[(size_t)m * N + n] = v + bf2f(resb[(size_t)m * N + n]);
        }
      }
    }
  }
}

// ---------------------------------------------------------------------------
// fused flash attention with RPE bias. No-max softmax, deferred row-sum.
// R9: swapped QK^T, 32 q-rows/wave, 4 waves/block covering 128 q-rows.
// Lane layout after mfma(K, Q): P[q = qs*16+l15][s = tn*16+quad*4+r].
// P LDS layout (per-wave 32x128B region): byte(q,s) =
//   q*128 + (((s>>3) ^ (q&7)) << 4) + (s&7)*2   (same family as R7, proven).
// PV reads it back as the A operand: 16B at ((ks*4+quad)^(q&7))<<4.
// ---------------------------------------------------------------------------
DEV floatx4 mfma16(bf16x8 a, bf16x8 b, floatx4 c) {
  return __builtin_amdgcn_mfma_f32_16x16x32_bf16(a, b, c, 0, 0, 0);
}

template <bool LAST>
DEV void qk_softmax(const ushort_t* __restrict__ Ksb, char* pw,
                    const unsigned (&bu)[2][4], const bf16x8 (&qf)[2][2],
                    float (&lsum)[2], float treg, int quad, int l15) {
  floatx4 sc[2][4];
  __builtin_amdgcn_s_setprio(1);
#pragma unroll
  for (int tn = 0; tn < 4; ++tn) {
    const int row = tn * 16 + l15;
    bf16x8 kf[2];
#pragma unroll
    for (int kq = 0; kq < 2; ++kq) {
      const int pos = (kq * 4 + quad) ^ (row & 7);
      kf[kq] = *(const bf16x8*)((const char*)Ksb + row * 128 + pos * 16);
    }
#pragma unroll
    for (int qs = 0; qs < 2; ++qs) {
      floatx4 z = {0.0f, 0.0f, 0.0f, 0.0f};
      z = mfma16(kf[0], qf[qs][0], z);
      z = mfma16(kf[1], qf[qs][1], z);
      sc[qs][tn] = z;
    }
  }
  __builtin_amdgcn_s_setprio(0);

#pragma unroll
  for (int qs = 0; qs < 2; ++qs) {
    const int qrow = qs * 16 + l15;
    char* prow = pw + qrow * 128;
    const int rx = l15 & 7;                      // qrow&7 == l15&7
#pragma unroll
    for (int tn = 0; tn < 4; ++tn) {
      float p[4];
#pragma unroll
      for (int r = 0; r < 4; ++r) {
        const int idx4 = (int)((bu[qs][r] >> (tn * 8)) & 255u);   // pre-scaled x4
        const float tv = __builtin_bit_cast(float,
            __builtin_amdgcn_ds_bpermute(idx4, __builtin_bit_cast(int, treg)));
        float pp = __builtin_amdgcn_exp2f(fmaf(sc[qs][tn][r], 0.18033688f, tv));
        if (LAST && (tn * 16 + quad * 4 + r >= 52)) pp = 0.0f;   // s >= 500
        lsum[qs] += pp;
        p[r] = pp;
      }
      // pack bf16 pairs (trunc): D = [hi(p1) : hi(p0)] via v_perm
#pragma unroll
      for (int rp = 0; rp < 2; ++rp) {
        const unsigned pk = __builtin_amdgcn_perm(
            __builtin_bit_cast(unsigned, p[rp * 2 + 1]),
            __builtin_bit_cast(unsigned, p[rp * 2]), 0x07060302u);
        // s_even = tn*16+quad*4+2rp: s>>3 = tn*2+(quad>>1), (s&7)*2 = (quad&1)*8+rp*4
        *(unsigned*)(prow + (((tn * 2 + (quad >> 1)) ^ rx) << 4)
                     + (quad & 1) * 8 + rp * 4) = pk;
      }
    }
  }
}

DEV void pv_acc(const ushort_t* __restrict__ Vsb, const char* pw,
                floatx4 (&o)[2][4], int quad, int l15) {
  __builtin_amdgcn_s_setprio(1);
#pragma unroll
  for (int ks = 0; ks < 2; ++ks) {
    bf16x8 vf[4];
#pragma unroll
    for (int nd = 0; nd < 4; ++nd) {
      const int row = nd * 16 + l15;
      const int pos = (ks * 4 + quad) ^ (row & 7);
      vf[nd] = *(const bf16x8*)((const char*)Vsb + row * 128 + pos * 16);
    }
#pragma unroll
    for (int qs = 0; qs < 2; ++qs) {
      const int qrow = qs * 16 + l15;
      const int ppos = (ks * 4 + quad) ^ (l15 & 7);
      const bf16x8 pfr = *(const bf16x8*)(pw + qrow * 128 + ppos * 16);
#pragma unroll
      for (int nd = 0; nd < 4; ++nd)
        o[qs][nd] = mfma16(pfr, vf[nd], o[qs][nd]);
    }
  }
  __builtin_amdgcn_s_setprio(0);
}

__global__ __launch_bounds__(256, 3) void attn_kernel(const ushort_t* __restrict__ qk,
                                                      const ushort_t* __restrict__ vt,
                                                      const unsigned char* __restrict__ bucket,
                                                      const float* __restrict__ rpe,
                                                      ushort_t* __restrict__ y) {
  const int bid = blockIdx.x;                  // 1024 blocks
  const int xcd = bid & 7, sl = bid >> 3;      // sl in [0,128)
  const int qt = sl & 3;
  const int pair = xcd * 32 + (sl >> 2);       // [0,256)
  const int h = pair >> 5, b = pair & 31;
  const int g = b >> 2;
  const int bpp = 8 * (b & 3) + h;

  __shared__ __align__(16) ushort_t Qs[128 * 64];    // 16K; reused as P (4x4K)
  __shared__ __align__(16) ushort_t Ks[2][64 * 64];  // 16K double buffer
  __shared__ __align__(16) ushort_t Vs[64 * 64];     // 8K single buffer

  const int tid = threadIdx.x;                 // [0,256)
  const int lane = tid & 63, w = tid >> 6;     // w in [0,4)
  const int quad = lane >> 4, l15 = lane & 15;
  const int t0 = qt * 128;

  // prologue: Q tile 128 rows (4 loads) + K tile 0 (2 loads)
#pragma unroll
  for (int j = 0; j < 4; ++j) {
    const int chunk = j * 256 + tid;
    const int row = chunk >> 3, pos = chunk & 7, c = pos ^ (row & 7);
    gload16(qk + (size_t)(b * T_ + t0 + row) * 1024 + h * 64 + c * 8,
            (char*)Qs + j * 4096 + w * 1024);
  }
#pragma unroll
  for (int j = 0; j < 2; ++j) {
    const int chunk = j * 256 + tid;
    const int row = chunk >> 3, pos = chunk & 7, c = pos ^ (row & 7);
    gload16(qk + (size_t)(b * T_ + row) * 1024 + 512 + h * 64 + c * 8,
            (char*)Ks[0] + j * 4096 + w * 1024);
  }

  // rpe table row -> one float per lane (lane i holds tbl[i]*log2e, i<49)
  const float treg = rpe[g * 49 + (lane < 49 ? lane : 48)] * 1.44269504f;

  // bucket bases: one uint4 per q-subtile per tile (16 contiguous bytes)
  const unsigned char* bkb[2];
#pragma unroll
  for (int qs = 0; qs < 2; ++qs) {
    const int tr = t0 + w * 32 + qs * 16 + l15;
    const int trc = (tr < T_) ? tr : (T_ - 1);
    bkb[qs] = bucket + ((size_t)(bpp * T_ + trc) << 9) + quad * 16;
  }
  unsigned bu[2][4];
  {
    const uint4 b0 = *(const uint4*)(bkb[0]);
    const uint4 b1 = *(const uint4*)(bkb[1]);
    bu[0][0] = b0.x; bu[0][1] = b0.y; bu[0][2] = b0.z; bu[0][3] = b0.w;
    bu[1][0] = b1.x; bu[1][1] = b1.y; bu[1][2] = b1.z; bu[1][3] = b1.w;
  }

  asm volatile("s_waitcnt vmcnt(0)" ::: "memory");
  __syncthreads();

  bf16x8 qf[2][2];
#pragma unroll
  for (int qs = 0; qs < 2; ++qs)
#pragma unroll
    for (int kq = 0; kq < 2; ++kq) {
      const int row = w * 32 + qs * 16 + l15;
      const int pos = (kq * 4 + quad) ^ (row & 7);
      qf[qs][kq] = *(const bf16x8*)((const char*)Qs + row * 128 + pos * 16);
    }

  floatx4 o[2][4] = {};
  float lsum[2] = {0.0f, 0.0f};
  char* pw = (char*)Qs + w * 4096;   // wave-private P region (32 rows x 128 B)

#pragma unroll 1
  for (int st = 0; st < 7; ++st) {
    const int cb = st & 1;
    __syncthreads();   // Vs free (prev PV done); Ks[cb^1] free (prev QK done)
    // issue V(st) + K(st+1); drained by mid-tile vmcnt after QK+softmax
#pragma unroll
    for (int j = 0; j < 2; ++j) {
      const int chunk = j * 256 + tid;
      const int row = chunk >> 3, pos = chunk & 7, c = pos ^ (row & 7);
      gload16(vt + ((size_t)(b * 8 + h) * 64 + row) * 512 + st * 64 + c * 8,
              (char*)Vs + j * 4096 + w * 1024);
      gload16(qk + (size_t)(b * T_ + (st + 1) * 64 + row) * 1024 + 512 + h * 64 + c * 8,
              (char*)Ks[cb ^ 1] + j * 4096 + w * 1024);
    }
    // prefetch next tile's bucket dwords (drained by mid-tile vmcnt too)
    const uint4 b0 = *(const uint4*)(bkb[0] + (st + 1) * 64);
    const uint4 b1 = *(const uint4*)(bkb[1] + (st + 1) * 64);

    qk_softmax<false>(Ks[cb], pw, bu, qf, lsum, treg, quad, l15);

    asm volatile("s_waitcnt vmcnt(0)" ::: "memory");
    __syncthreads();

    pv_acc(Vs, pw, o, quad, l15);

    bu[0][0] = b0.x; bu[0][1] = b0.y; bu[0][2] = b0.z; bu[0][3] = b0.w;
    bu[1][0] = b1.x; bu[1][1] = b1.y; bu[1][2] = b1.z; bu[1][3] = b1.w;
  }
  // final tile (st=7, Ks[1]) with s>=500 masking
  __syncthreads();
#pragma unroll
  for (int j = 0; j < 2; ++j) {
    const int chunk = j * 256 + tid;
    const int row = chunk >> 3, pos = chunk & 7, c = pos ^ (row & 7);
    gload16(vt + ((size_t)(b * 8 + h) * 64 + row) * 512 + 448 + c * 8,
            (char*)Vs + j * 4096 + w * 1024);
  }
  qk_softmax<true>(Ks[1], pw, bu, qf, lsum, treg, quad, l15);
  asm volatile("s_waitcnt vmcnt(0)" ::: "memory");
  __syncthreads();
  pv_acc(Vs, pw, o, quad, l15);

  // row-sum reduce (lane holds sum for q = qs*16+l15 after 2 shuffles)
  float lr[2];
#pragma unroll
  for (int qs = 0; qs < 2; ++qs) {
    float s = lsum[qs];
    s += __shfl_xor(s, 16);
    s += __shfl_xor(s, 32);
    lr[qs] = s;
  }
  // o rows are q = qs*16 + quad*4 + r -> fetch that row's sum from lane quad*4+r
#pragma unroll
  for (int qs = 0; qs < 2; ++qs)
#pragma unroll
    for (int r = 0; r < 4; ++r) {
      const float sv = __shfl(lr[qs], quad * 4 + r);
      const int t = t0 + w * 32 + qs * 16 + quad * 4 + r;
      if (t < T_) {
        const float inv = 1.0f / sv;
#pragma unroll
        for (int nd = 0; nd < 4; ++nd)
          y[((size_t)b * T_ + t) * 512 + h * 64 + nd * 16 + l15] =
              f2bf(o[qs][nd][r] * inv);
      }
    }
}

// ---------------------------------------------------------------------------
// LayerNorm: one wave per row (8 f32/lane via 2x float4), no LDS, no barrier.
// grid 4000 x 256 threads = 4 rows/block.
// ---------------------------------------------------------------------------
__global__ __launch_bounds__(256) void ln_kernel(const float* z,
                                                 const float* __restrict__ gw,
                                                 const float* __restrict__ gb,
                                                 ushort_t* out_bf, float* out_f) {
  const int tid = threadIdx.x, lane = tid & 63, w = tid >> 6;
  const int row = blockIdx.x * 4 + w;
  const float* zr = z + (size_t)row * 512;
  const int c0 = lane * 8;
  const float4 v0 = *(const float4*)(zr + c0);
  const float4 v1 = *(const float4*)(zr + c0 + 4);
  float s = ((v0.x + v0.y) + (v0.z + v0.w)) + ((v1.x + v1.y) + (v1.z + v1.w));
#pragma unroll
  for (int m = 1; m < 64; m <<= 1) s += __shfl_xor(s, m);
  const float mean = s * (1.0f / 512.0f);
  float d[8] = { v0.x - mean, v0.y - mean, v0.z - mean, v0.w - mean,
                 v1.x - mean, v1.y - mean, v1.z - mean, v1.w - mean };
  float q = 0.0f;
#pragma unroll
  for (int j = 0; j < 8; ++j) q += d[j] * d[j];
#pragma unroll
  for (int m = 1; m < 64; m <<= 1) q += __shfl_xor(q, m);
  const float rstd = rsqrtf(q * (1.0f / 512.0f) + 1e-5f);
  const float4 ga = *(const float4*)(gw + c0);
  const float4 gc = *(const float4*)(gw + c0 + 4);
  const float4 ba = *(const float4*)(gb + c0);
  const float4 bc = *(const float4*)(gb + c0 + 4);
  float ov[8];
  ov[0] = d[0] * rstd * ga.x + ba.x;
  ov[1] = d[1] * rstd * ga.y + ba.y;
  ov[2] = d[2] * rstd * ga.z + ba.z;
  ov[3] = d[3] * rstd * ga.w + ba.w;
  ov[4] = d[4] * rstd * gc.x + bc.x;
  ov[5] = d[5] * rstd * gc.y + bc.y;
  ov[6] = d[6] * rstd * gc.z + bc.z;
  ov[7] = d[7] * rstd * gc.w + bc.w;
  if (out_bf) {
    ushort8v pk;
#pragma unroll
    for (int j = 0; j < 8; ++j) pk[j] = f2bf(ov[j]);
    *(ushort8v*)(out_bf + (size_t)row * 512 + c0) = pk;
  }
  if (out_f) {
    float4 o0 = { ov[0], ov[1], ov[2], ov[3] };
    float4 o1 = { ov[4], ov[5], ov[6], ov[7] };
    *(float4*)(out_f + (size_t)row * 512 + c0) = o0;
    *(float4*)(out_f + (size_t)row * 512 + c0 + 4) = o1;
  }
}

// ---------------------------------------------------------------------------
extern "C" void kernel_launch(void* const* d_in, const int* in_sizes, int n_in,
                              void* d_out, int out_size, void* d_ws, size_t ws_size,
                              hipStream_t stream) {
  (void)in_sizes; (void)n_in; (void)out_size; (void)ws_size;
  const float* x      = (const float*)d_in[0];
  const int*   ct     = (const int*)d_in[1];
  const float* w_attn = (const float*)d_in[2];
  const float* b_attn = (const float*)d_in[3];
  const float* w_proj = (const float*)d_in[4];
  const float* b_proj = (const float*)d_in[5];
  const float* rpe    = (const float*)d_in[6];
  const float* ln1w   = (const float*)d_in[7];
  const float* ln1b   = (const float*)d_in[8];
  const float* ln2w   = (const float*)d_in[9];
  const float* ln2b   = (const float*)d_in[10];
  const float* w_fc   = (const float*)d_in[11];
  const float* b_fc   = (const float*)d_in[12];
  const float* w_fc2  = (const float*)d_in[13];
  const float* b_fc2  = (const float*)d_in[14];
  float* out = (float*)d_out;

  char* ws = (char*)d_ws;
  ushort_t* qk      = (ushort_t*)(ws + OFF_QK);
  ushort_t* h_buf   = (ushort_t*)(ws + OFF_QK);     // reuse after attention
  ushort_t* x_bf    = (ushort_t*)(ws + OFF_XBF);
  ushort_t* x1      = (ushort_t*)(ws + OFF_XBF);    // reuse after qkv GEMM
  unsigned char* bk = (unsigned char*)(ws + OFF_BUCKET);
  ushort_t* vt      = (ushort_t*)(ws + OFF_VT);
  ushort_t* y       = (ushort_t*)(ws + OFF_Y);
  ushort_t* wt_attn = (ushort_t*)(ws + OFF_WATTN);
  ushort_t* wt_proj = (ushort_t*)(ws + OFF_WPROJ);
  ushort_t* wt_fc   = (ushort_t*)(ws + OFF_WFC);
  ushort_t* wt_fc2  = (ushort_t*)(ws + OFF_WFC2);

  cvt_bf16<<<dim3(8000), 256, 0, stream>>>(x, x_bf, M_ * C_);
  WTArgs wta;
  wta.d[0] = { w_attn, wt_attn, 512, 1536 };
  wta.d[1] = { w_proj, wt_proj, 512, 512 };
  wta.d[2] = { w_fc,   wt_fc,   512, 1024 };
  wta.d[3] = { w_fc2,  wt_fc2,  1024, 512 };
  wtrans_all<<<dim3(2048), 256, 0, stream>>>(wta);
  bucket_kernel<<<dim3(125, 32), 256, 0, stream>>>(ct, bk);
  hipMemsetAsync(vt, 0, VT_BYTES, stream);   // zero the s in [500,512) pad

  // qk = (x@w_attn+b)[q,k cols]; vt = transposed v cols   (grid 8*16*12)
  gemm_qkv<<<dim3(1536), 256, 0, stream>>>(x_bf, wt_attn, b_attn, qk, vt);
  attn_kernel<<<dim3(1024), 256, 0, stream>>>(qk, vt, bk, rpe, y);
  // z = x + y @ w_proj + b_proj  (f32, into d_out)   (grid 8*16*8)
  gemm_bt<64, 2><<<dim3(1024), 256, 0, stream>>>(y, wt_proj, b_proj, x, nullptr, out, 512, 512);
  ln_kernel<<<dim3(4000), 256, 0, stream>>>(out, ln1w, ln1b, x1, nullptr);
  // h = gelu(x1 @ w_fc + b_fc)   (grid 8*16*16, 128x64 tiles, 4 blocks/CU)
  gemm_bt<64, 1><<<dim3(2048), 256, 0, stream>>>(x1, wt_fc, b_fc, nullptr, nullptr, h_buf, 1024, 512);
  // z2 = x1 + h @ w_fc2 + b_fc2   (grid 8*16*8)
  gemm_bt<64, 3><<<dim3(1024), 256, 0, stream>>>(h_buf, wt_fc2, b_fc2, nullptr, x1, out, 512, 1024);
  ln_kernel<<<dim3(4000), 256, 0, stream>>>(out, ln2w, ln2b, nullptr, out);
}

// Round 13
// 298.451 us; speedup vs baseline: 1.0003x; 1.0003x over previous
//
#include <hip/hip_runtime.h>
#include <cstdint>
#include <cstddef>

// ---------------------------------------------------------------------------
// Block_85375359910651: RPE-attention transformer block on gfx950.
// B=32 T=500 C=512 H=8 D=64, buckets=49. bf16 MFMA pipeline (threshold 0.106).
// rpe[b,h,t,s] == rpe_table[b//4, bucket[8*(b%4)+h, t, s]]
// R16 = R15 byte-identical resubmit (second wall sample; channels conflict):
//   per-dispatch: FC1 gemm_bt<128,1> was 78us WRITE-BOUND (75MB writes =
//   2.3x logical 32.8MB: bf16 scalar stores -> 32B partial-line RMW);
//   as gemm_bt<64,1> it left the top-5 entirely (<43.5us, >=35us gain).
//   wall: 283.7 -> 298.6 (+15) CONTRADICTS; session noise band is +-8-15us
//   (same source measured 283.7 and 289.0). Re-measure before reverting.
//   attn rows bit-identical across rounds (43.5us, 1.05M conflicts).
// ---------------------------------------------------------------------------

typedef unsigned short ushort_t;
typedef __bf16 bf16x8 __attribute__((ext_vector_type(8)));
typedef float floatx4 __attribute__((ext_vector_type(4)));
typedef unsigned short ushort4v __attribute__((ext_vector_type(4)));
typedef unsigned short ushort8v __attribute__((ext_vector_type(8)));

#define DEV __device__ __forceinline__

#define B_ 32
#define T_ 500
#define C_ 512
#define H_ 8
#define M_ 16000      // B*T

// ---- workspace layout (bytes), total ~94.7 MB ----
#define OFF_QK     0ULL            // 16016*1024*2 = 32,800,768  (later: h 16000*1024*2)
#define OFF_XBF    32800768ULL     // 16,384,000                 (later: x1)
#define OFF_BUCKET 49184768ULL     // 8,192,000   u8 (32,500,512) permuted
#define OFF_VT     57376768ULL     // 16,777,216  bf16 (32,8,64,512)
#define OFF_Y      74153984ULL     // 16,384,000  bf16 attn out
#define OFF_WATTN  90537984ULL     // 1,572,864   bf16 (1536,512)
#define OFF_WPROJ  92110848ULL     // 524,288     bf16 (512,512)
#define OFF_WFC    92635136ULL     // 1,048,576   bf16 (1024,512)
#define OFF_WFC2   93683712ULL     // 1,048,576   bf16 (512,1024)
#define VT_BYTES   16777216ULL

DEV ushort_t f2bf(float f) {
  union { float f; unsigned u; } v; v.f = f;
  unsigned r = v.u + 0x7fffu + ((v.u >> 16) & 1u);   // RNE
  return (ushort_t)(r >> 16);
}
DEV float bf2f(ushort_t u) {
  union { unsigned u; float f; } v; v.u = ((unsigned)u) << 16;
  return v.f;
}

DEV void gload16(const void* g, void* l) {
  __builtin_amdgcn_global_load_lds(
      (__attribute__((address_space(1))) void*)(g),
      (__attribute__((address_space(3))) void*)(l), 16, 0, 0);
}

// ---------------------------------------------------------------------------
__global__ __launch_bounds__(256) void cvt_bf16(const float* __restrict__ in,
                                                ushort_t* __restrict__ out, int n) {
  int i = (blockIdx.x * 256 + threadIdx.x) * 4;
  if (i >= n) return;
  float4 v = *(const float4*)(in + i);
  ushort4v o = { f2bf(v.x), f2bf(v.y), f2bf(v.z), f2bf(v.w) };
  *(ushort4v*)(out + i) = o;
}

// ---------------------------------------------------------------------------
// All four weight transposes in one launch. (K,N) fp32 -> (N,K) bf16.
// ---------------------------------------------------------------------------
struct WTDesc { const float* w; ushort_t* wt; int K; int N; };
struct WTArgs { WTDesc d[4]; };

__global__ __launch_bounds__(256) void wtrans_all(WTArgs a) {
  const int bid = blockIdx.x;
  int z, local;
  if (bid < 768)       { z = 0; local = bid; }
  else if (bid < 1024) { z = 1; local = bid - 768; }
  else if (bid < 1536) { z = 2; local = bid - 1024; }
  else                 { z = 3; local = bid - 1536; }
  const WTDesc dd = a.d[z];
  const int gx = dd.N >> 5;
  const int n0 = (local % gx) * 32, k0 = (local / gx) * 32;

  __shared__ float tile[32][33];
  const int c = threadIdx.x & 31, r = threadIdx.x >> 5;
#pragma unroll
  for (int rr = 0; rr < 4; ++rr)
    tile[r + rr * 8][c] = dd.w[(size_t)(k0 + r + rr * 8) * dd.N + n0 + c];
  __syncthreads();
#pragma unroll
  for (int rr = 0; rr < 4; ++rr)
    dd.wt[(size_t)(n0 + r + rr * 8) * dd.K + k0 + c] = f2bf(tile[c][r + rr * 8]);
}

// ---------------------------------------------------------------------------
// bucket ids, PERMUTED layout: row stride 512; within 64-col block, byte at
// (s&15)*4 + ((s>>4)&3) holds column s. Byte value PRE-SCALED x4 (bpermute
// byte address). Consumer (swapped-QK layout) reads one uint4 at quad*16:
// byte (r*4+tn) = s = tn*16+quad*4+r  -> 16 needed bytes are contiguous.
// grid (125, 32): ct row staged in LDS, wave w handles t = bx*4 + w.
// ---------------------------------------------------------------------------
__global__ __launch_bounds__(256) void bucket_kernel(const int* __restrict__ ct,
                                                     unsigned char* __restrict__ bucket) {
  const int b = blockIdx.y;
  const int tid = threadIdx.x, w = tid >> 6, lane = tid & 63;
  __shared__ int2 ctS[500];
  for (int j = tid; j < T_; j += 256) ctS[j] = ((const int2*)ct)[(size_t)b * T_ + j];
  __syncthreads();
  const int t = blockIdx.x * 4 + w;
  const int2 a = ctS[t];
  const float ax = (float)a.x, ay = (float)a.y;
  const size_t rowbase = (size_t)(b * T_ + t) << 9;
#pragma unroll
  for (int it = 0; it < 8; ++it) {
    const int s = it * 64 + lane;
    if (s < T_) {
      const int2 c2 = ctS[s];
      const float dx = ax - (float)c2.x, dy = ay - (float)c2.y;
      const float dist = __builtin_amdgcn_sqrtf(dx * dx + dy * dy);
      const float rel = truncf(dist * (1.0f / 12.0f));
      const float far = fminf(
          rintf(fmaf(__builtin_amdgcn_logf(rel * (1.0f / 12.0f)), 4.0f, 12.0f)), 24.0f);
      const float idx = (rel <= 12.0f) ? rel : far;
      bucket[rowbase + (s >> 6) * 64 + (s & 15) * 4 + ((s >> 4) & 3)]
          = (unsigned char)(((int)idx + 24) << 2);   // pre-scaled byte addr
    }
  }
}

// ---------------------------------------------------------------------------
// qkv GEMM with fused V-transpose epilogue. A(M x 512) * Wt(1536 x 512)^T.
// Flat grid 1536 = 8 xcd * 16 mg * 12 n, XCD-swizzled.
// ---------------------------------------------------------------------------
__global__ __launch_bounds__(256, 2)
void gemm_qkv(const ushort_t* __restrict__ A,
              const ushort_t* __restrict__ Bt,
              const float* __restrict__ bias,
              ushort_t* __restrict__ qk,
              ushort_t* __restrict__ vt) {
  constexpr int K = 512;
  const int bid = blockIdx.x;
  const int xcd = bid & 7, k = bid >> 3;
  const int n_blk = k % 12, mg = k / 12;
  const int m_blk = mg * 8 + xcd;
  if (m_blk >= 125) return;
  const int m0 = m_blk * 128, n0 = n_blk * 128;

  __shared__ __align__(16) ushort_t As[128 * 64];
  __shared__ __align__(16) ushort_t Bs[128 * 64];
  const int tid = threadIdx.x;
  const int lane = tid & 63, w = tid >> 6;
  const int wm = w >> 1, wn = w & 1;
  const int quad = lane >> 4, l15 = lane & 15;

  floatx4 acc[4][4] = {};

  for (int k0 = 0; k0 < K; k0 += 64) {
    __syncthreads();
#pragma unroll
    for (int j = 0; j < 4; ++j) {
      const int chunk = j * 256 + tid;
      const int row = chunk >> 3, pos = chunk & 7, c = pos ^ (row & 7);
      gload16(A + (size_t)(m0 + row) * K + k0 + c * 8, (char*)As + j * 4096 + w * 1024);
      gload16(Bt + (size_t)(n0 + row) * K + k0 + c * 8, (char*)Bs + j * 4096 + w * 1024);
    }
    asm volatile("s_waitcnt vmcnt(0)" ::: "memory");
    __syncthreads();

#pragma unroll
    for (int kq = 0; kq < 2; ++kq) {
      bf16x8 af[4], bfr[4];
#pragma unroll
      for (int t = 0; t < 4; ++t) {
        const int rowa = wm * 64 + t * 16 + l15;
        const int posa = (kq * 4 + quad) ^ (rowa & 7);
        af[t] = *(const bf16x8*)((const char*)As + rowa * 128 + posa * 16);
        const int rowb = wn * 64 + t * 16 + l15;
        const int posb = (kq * 4 + quad) ^ (rowb & 7);
        bfr[t] = *(const bf16x8*)((const char*)Bs + rowb * 128 + posb * 16);
      }
#pragma unroll
      for (int tm = 0; tm < 4; ++tm)
#pragma unroll
        for (int tn = 0; tn < 4; ++tn)
          acc[tm][tn] = __builtin_amdgcn_mfma_f32_16x16x32_bf16(af[tm], bfr[tn], acc[tm][tn], 0, 0, 0);
    }
  }

  if (n0 < 1024) {   // Q,K path (uniform per block)
#pragma unroll
    for (int tn = 0; tn < 4; ++tn) {
      const int n = n0 + wn * 64 + tn * 16 + l15;
      const float bs = bias[n];
#pragma unroll
      for (int tm = 0; tm < 4; ++tm)
#pragma unroll
        for (int r = 0; r < 4; ++r) {
          const int m = m0 + wm * 64 + tm * 16 + quad * 4 + r;
          qk[(size_t)m * 1024 + n] = f2bf(acc[tm][tn][r] + bs);
        }
    }
  } else {           // V path: transpose into vt
#pragma unroll
    for (int tn = 0; tn < 4; ++tn) {
      const int n = n0 + wn * 64 + tn * 16 + l15;
      const float bs = bias[n];
      const int hh = (n >> 6) - 16, dd = n & 63;
#pragma unroll
      for (int tm = 0; tm < 4; ++tm) {
        const int mb = m0 + wm * 64 + tm * 16 + quad * 4;
        const int bb = mb / 500;
        const int ss = mb - bb * 500;
        ushort4v pk;
#pragma unroll
        for (int r = 0; r < 4; ++r) pk[r] = f2bf(acc[tm][tn][r] + bs);
        *(ushort4v*)(vt + (((size_t)(bb * 8 + hh)) * 64 + dd) * 512 + ss) = pk;
      }
    }
  }
}

// ---------------------------------------------------------------------------
// GEMM: C(M x N) = A(M x K) * Bt(N x K)^T.  128 x TN tile, BK=64, XCD swizzle.
// Flat grid 8 * 16 * (N/TN). EPI 1: bf16(gelu)  2: f32(+resf)  3: f32(+resb)
// ---------------------------------------------------------------------------
template <int TN, int EPI>
__global__ __launch_bounds__(256, TN == 64 ? 4 : 2)
void gemm_bt(const ushort_t* __restrict__ A,
             const ushort_t* __restrict__ Bt,
             const float* __restrict__ bias,
             const float* __restrict__ resf,
             const ushort_t* __restrict__ resb,
             void* __restrict__ outp,
             int N, int K) {
  constexpr int TMW = (TN == 128) ? 4 : 2;
  const int nn = N / TN;
  const int bid = blockIdx.x;
  const int xcd = bid & 7, kk = bid >> 3;
  const int n_blk = kk % nn, mg = kk / nn;
  const int m_blk = mg * 8 + xcd;
  if (m_blk >= 125) return;
  const int m0 = m_blk * 128, n0 = n_blk * TN;

  __shared__ __align__(16) ushort_t As[128 * 64];
  __shared__ __align__(16) ushort_t Bs[TN * 64];
  const int tid = threadIdx.x;
  const int lane = tid & 63, w = tid >> 6;
  const int wm = (TN == 128) ? (w >> 1) : w;
  const int wn = (TN == 128) ? (w & 1) : 0;
  const int quad = lane >> 4, l15 = lane & 15;

  floatx4 acc[TMW][4] = {};

  for (int k0 = 0; k0 < K; k0 += 64) {
    __syncthreads();
#pragma unroll
    for (int j = 0; j < 4; ++j) {
      const int chunk = j * 256 + tid;
      const int row = chunk >> 3, pos = chunk & 7, c = pos ^ (row & 7);
      gload16(A + (size_t)(m0 + row) * K + k0 + c * 8, (char*)As + j * 4096 + w * 1024);
    }
#pragma unroll
    for (int j = 0; j < TN / 32; ++j) {
      const int chunk = j * 256 + tid;
      const int row = chunk >> 3, pos = chunk & 7, c = pos ^ (row & 7);
      gload16(Bt + (size_t)(n0 + row) * K + k0 + c * 8, (char*)Bs + j * 4096 + w * 1024);
    }
    asm volatile("s_waitcnt vmcnt(0)" ::: "memory");
    __syncthreads();

#pragma unroll
    for (int kq = 0; kq < 2; ++kq) {
      bf16x8 af[TMW], bfr[4];
#pragma unroll
      for (int t = 0; t < TMW; ++t) {
        const int row = wm * (TMW * 16) + t * 16 + l15;
        const int pos = (kq * 4 + quad) ^ (row & 7);
        af[t] = *(const bf16x8*)((const char*)As + row * 128 + pos * 16);
      }
#pragma unroll
      for (int t = 0; t < 4; ++t) {
        const int row = wn * 64 + t * 16 + l15;
        const int pos = (kq * 4 + quad) ^ (row & 7);
        bfr[t] = *(const bf16x8*)((const char*)Bs + row * 128 + pos * 16);
      }
#pragma unroll
      for (int tm = 0; tm < TMW; ++tm)
#pragma unroll
        for (int tn = 0; tn < 4; ++tn)
          acc[tm][tn] = __builtin_amdgcn_mfma_f32_16x16x32_bf16(af[tm], bfr[tn], acc[tm][tn], 0, 0, 0);
    }
  }

#pragma unroll
  for (int tn = 0; tn < 4; ++tn) {
    const int n = n0 + wn * 64 + tn * 16 + l15;
    const float bs = bias[n];
#pragma unroll
    for (int tm = 0; tm < TMW; ++tm) {
#pragma unroll
      for (int r = 0; r < 4; ++r) {
        const int m = m0 + wm * (TMW * 16) + tm * 16 + quad * 4 + r;
        const float v = acc[tm][tn][r] + bs;
        if (EPI == 1) {
          const float gv = 0.5f * v * (1.0f + erff(v * 0.70710678118654752f));
          ((ushort_t*)outp)[(size_t)m * N + n] = f2bf(gv);
        } else if (EPI == 2) {
          ((float*)outp)[(size_t)m * N + n] = v + resf[(size_t)m * N + n];
        } else {
          ((float*)outp)[(size_t)m * N + n] = v + bf2f(resb[(size_t)m * N + n]);
        }
      }
    }
  }
}

// ---------------------------------------------------------------------------
// fused flash attention with RPE bias. No-max softmax, deferred row-sum.
// R9: swapped QK^T, 32 q-rows/wave, 4 waves/block covering 128 q-rows.
// Lane layout after mfma(K, Q): P[q = qs*16+l15][s = tn*16+quad*4+r].
// P LDS layout (per-wave 32x128B region): byte(q,s) =
//   q*128 + (((s>>3) ^ (q&7)) << 4) + (s&7)*2   (same family as R7, proven).
// PV reads it back as the A operand: 16B at ((ks*4+quad)^(q&7))<<4.
// ---------------------------------------------------------------------------
DEV floatx4 mfma16(bf16x8 a, bf16x8 b, floatx4 c) {
  return __builtin_amdgcn_mfma_f32_16x16x32_bf16(a, b, c, 0, 0, 0);
}

template <bool LAST>
DEV void qk_softmax(const ushort_t* __restrict__ Ksb, char* pw,
                    const unsigned (&bu)[2][4], const bf16x8 (&qf)[2][2],
                    float (&lsum)[2], float treg, int quad, int l15) {
  floatx4 sc[2][4];
  __builtin_amdgcn_s_setprio(1);
#pragma unroll
  for (int tn = 0; tn < 4; ++tn) {
    const int row = tn * 16 + l15;
    bf16x8 kf[2];
#pragma unroll
    for (int kq = 0; kq < 2; ++kq) {
      const int pos = (kq * 4 + quad) ^ (row & 7);
      kf[kq] = *(const bf16x8*)((const char*)Ksb + row * 128 + pos * 16);
    }
#pragma unroll
    for (int qs = 0; qs < 2; ++qs) {
      floatx4 z = {0.0f, 0.0f, 0.0f, 0.0f};
      z = mfma16(kf[0], qf[qs][0], z);
      z = mfma16(kf[1], qf[qs][1], z);
      sc[qs][tn] = z;
    }
  }
  __builtin_amdgcn_s_setprio(0);

#pragma unroll
  for (int qs = 0; qs < 2; ++qs) {
    const int qrow = qs * 16 + l15;
    char* prow = pw + qrow * 128;
    const int rx = l15 & 7;                      // qrow&7 == l15&7
#pragma unroll
    for (int tn = 0; tn < 4; ++tn) {
      float p[4];
#pragma unroll
      for (int r = 0; r < 4; ++r) {
        const int idx4 = (int)((bu[qs][r] >> (tn * 8)) & 255u);   // pre-scaled x4
        const float tv = __builtin_bit_cast(float,
            __builtin_amdgcn_ds_bpermute(idx4, __builtin_bit_cast(int, treg)));
        float pp = __builtin_amdgcn_exp2f(fmaf(sc[qs][tn][r], 0.18033688f, tv));
        if (LAST && (tn * 16 + quad * 4 + r >= 52)) pp = 0.0f;   // s >= 500
        lsum[qs] += pp;
        p[r] = pp;
      }
      // pack bf16 pairs (trunc): D = [hi(p1) : hi(p0)] via v_perm
#pragma unroll
      for (int rp = 0; rp < 2; ++rp) {
        const unsigned pk = __builtin_amdgcn_perm(
            __builtin_bit_cast(unsigned, p[rp * 2 + 1]),
            __builtin_bit_cast(unsigned, p[rp * 2]), 0x07060302u);
        // s_even = tn*16+quad*4+2rp: s>>3 = tn*2+(quad>>1), (s&7)*2 = (quad&1)*8+rp*4
        *(unsigned*)(prow + (((tn * 2 + (quad >> 1)) ^ rx) << 4)
                     + (quad & 1) * 8 + rp * 4) = pk;
      }
    }
  }
}

DEV void pv_acc(const ushort_t* __restrict__ Vsb, const char* pw,
                floatx4 (&o)[2][4], int quad, int l15) {
  __builtin_amdgcn_s_setprio(1);
#pragma unroll
  for (int ks = 0; ks < 2; ++ks) {
    bf16x8 vf[4];
#pragma unroll
    for (int nd = 0; nd < 4; ++nd) {
      const int row = nd * 16 + l15;
      const int pos = (ks * 4 + quad) ^ (row & 7);
      vf[nd] = *(const bf16x8*)((const char*)Vsb + row * 128 + pos * 16);
    }
#pragma unroll
    for (int qs = 0; qs < 2; ++qs) {
      const int qrow = qs * 16 + l15;
      const int ppos = (ks * 4 + quad) ^ (l15 & 7);
      const bf16x8 pfr = *(const bf16x8*)(pw + qrow * 128 + ppos * 16);
#pragma unroll
      for (int nd = 0; nd < 4; ++nd)
        o[qs][nd] = mfma16(pfr, vf[nd], o[qs][nd]);
    }
  }
  __builtin_amdgcn_s_setprio(0);
}

__global__ __launch_bounds__(256, 3) void attn_kernel(const ushort_t* __restrict__ qk,
                                                      const ushort_t* __restrict__ vt,
                                                      const unsigned char* __restrict__ bucket,
                                                      const float* __restrict__ rpe,
                                                      ushort_t* __restrict__ y) {
  const int bid = blockIdx.x;                  // 1024 blocks
  const int xcd = bid & 7, sl = bid >> 3;      // sl in [0,128)
  const int qt = sl & 3;
  const int pair = xcd * 32 + (sl >> 2);       // [0,256)
  const int h = pair >> 5, b = pair & 31;
  const int g = b >> 2;
  const int bpp = 8 * (b & 3) + h;

  __shared__ __align__(16) ushort_t Qs[128 * 64];    // 16K; reused as P (4x4K)
  __shared__ __align__(16) ushort_t Ks[2][64 * 64];  // 16K double buffer
  __shared__ __align__(16) ushort_t Vs[64 * 64];     // 8K single buffer

  const int tid = threadIdx.x;                 // [0,256)
  const int lane = tid & 63, w = tid >> 6;     // w in [0,4)
  const int quad = lane >> 4, l15 = lane & 15;
  const int t0 = qt * 128;

  // prologue: Q tile 128 rows (4 loads) + K tile 0 (2 loads)
#pragma unroll
  for (int j = 0; j < 4; ++j) {
    const int chunk = j * 256 + tid;
    const int row = chunk >> 3, pos = chunk & 7, c = pos ^ (row & 7);
    gload16(qk + (size_t)(b * T_ + t0 + row) * 1024 + h * 64 + c * 8,
            (char*)Qs + j * 4096 + w * 1024);
  }
#pragma unroll
  for (int j = 0; j < 2; ++j) {
    const int chunk = j * 256 + tid;
    const int row = chunk >> 3, pos = chunk & 7, c = pos ^ (row & 7);
    gload16(qk + (size_t)(b * T_ + row) * 1024 + 512 + h * 64 + c * 8,
            (char*)Ks[0] + j * 4096 + w * 1024);
  }

  // rpe table row -> one float per lane (lane i holds tbl[i]*log2e, i<49)
  const float treg = rpe[g * 49 + (lane < 49 ? lane : 48)] * 1.44269504f;

  // bucket bases: one uint4 per q-subtile per tile (16 contiguous bytes)
  const unsigned char* bkb[2];
#pragma unroll
  for (int qs = 0; qs < 2; ++qs) {
    const int tr = t0 + w * 32 + qs * 16 + l15;
    const int trc = (tr < T_) ? tr : (T_ - 1);
    bkb[qs] = bucket + ((size_t)(bpp * T_ + trc) << 9) + quad * 16;
  }
  unsigned bu[2][4];
  {
    const uint4 b0 = *(const uint4*)(bkb[0]);
    const uint4 b1 = *(const uint4*)(bkb[1]);
    bu[0][0] = b0.x; bu[0][1] = b0.y; bu[0][2] = b0.z; bu[0][3] = b0.w;
    bu[1][0] = b1.x; bu[1][1] = b1.y; bu[1][2] = b1.z; bu[1][3] = b1.w;
  }

  asm volatile("s_waitcnt vmcnt(0)" ::: "memory");
  __syncthreads();

  bf16x8 qf[2][2];
#pragma unroll
  for (int qs = 0; qs < 2; ++qs)
#pragma unroll
    for (int kq = 0; kq < 2; ++kq) {
      const int row = w * 32 + qs * 16 + l15;
      const int pos = (kq * 4 + quad) ^ (row & 7);
      qf[qs][kq] = *(const bf16x8*)((const char*)Qs + row * 128 + pos * 16);
    }

  floatx4 o[2][4] = {};
  float lsum[2] = {0.0f, 0.0f};
  char* pw = (char*)Qs + w * 4096;   // wave-private P region (32 rows x 128 B)

#pragma unroll 1
  for (int st = 0; st < 7; ++st) {
    const int cb = st & 1;
    __syncthreads();   // Vs free (prev PV done); Ks[cb^1] free (prev QK done)
    // issue V(st) + K(st+1); drained by mid-tile vmcnt after QK+softmax
#pragma unroll
    for (int j = 0; j < 2; ++j) {
      const int chunk = j * 256 + tid;
      const int row = chunk >> 3, pos = chunk & 7, c = pos ^ (row & 7);
      gload16(vt + ((size_t)(b * 8 + h) * 64 + row) * 512 + st * 64 + c * 8,
              (char*)Vs + j * 4096 + w * 1024);
      gload16(qk + (size_t)(b * T_ + (st + 1) * 64 + row) * 1024 + 512 + h * 64 + c * 8,
              (char*)Ks[cb ^ 1] + j * 4096 + w * 1024);
    }
    // prefetch next tile's bucket dwords (drained by mid-tile vmcnt too)
    const uint4 b0 = *(const uint4*)(bkb[0] + (st + 1) * 64);
    const uint4 b1 = *(const uint4*)(bkb[1] + (st + 1) * 64);

    qk_softmax<false>(Ks[cb], pw, bu, qf, lsum, treg, quad, l15);

    asm volatile("s_waitcnt vmcnt(0)" ::: "memory");
    __syncthreads();

    pv_acc(Vs, pw, o, quad, l15);

    bu[0][0] = b0.x; bu[0][1] = b0.y; bu[0][2] = b0.z; bu[0][3] = b0.w;
    bu[1][0] = b1.x; bu[1][1] = b1.y; bu[1][2] = b1.z; bu[1][3] = b1.w;
  }
  // final tile (st=7, Ks[1]) with s>=500 masking
  __syncthreads();
#pragma unroll
  for (int j = 0; j < 2; ++j) {
    const int chunk = j * 256 + tid;
    const int row = chunk >> 3, pos = chunk & 7, c = pos ^ (row & 7);
    gload16(vt + ((size_t)(b * 8 + h) * 64 + row) * 512 + 448 + c * 8,
            (char*)Vs + j * 4096 + w * 1024);
  }
  qk_softmax<true>(Ks[1], pw, bu, qf, lsum, treg, quad, l15);
  asm volatile("s_waitcnt vmcnt(0)" ::: "memory");
  __syncthreads();
  pv_acc(Vs, pw, o, quad, l15);

  // row-sum reduce (lane holds sum for q = qs*16+l15 after 2 shuffles)
  float lr[2];
#pragma unroll
  for (int qs = 0; qs < 2; ++qs) {
    float s = lsum[qs];
    s += __shfl_xor(s, 16);
    s += __shfl_xor(s, 32);
    lr[qs] = s;
  }
  // o rows are q = qs*16 + quad*4 + r -> fetch that row's sum from lane quad*4+r
#pragma unroll
  for (int qs = 0; qs < 2; ++qs)
#pragma unroll
    for (int r = 0; r < 4; ++r) {
      const float sv = __shfl(lr[qs], quad * 4 + r);
      const int t = t0 + w * 32 + qs * 16 + quad * 4 + r;
      if (t < T_) {
        const float inv = 1.0f / sv;
#pragma unroll
        for (int nd = 0; nd < 4; ++nd)
          y[((size_t)b * T_ + t) * 512 + h * 64 + nd * 16 + l15] =
              f2bf(o[qs][nd][r] * inv);
      }
    }
}

// ---------------------------------------------------------------------------
// LayerNorm: one wave per row (8 f32/lane via 2x float4), no LDS, no barrier.
// grid 4000 x 256 threads = 4 rows/block.
// ---------------------------------------------------------------------------
__global__ __launch_bounds__(256) void ln_kernel(const float* z,
                                                 const float* __restrict__ gw,
                                                 const float* __restrict__ gb,
                                                 ushort_t* out_bf, float* out_f) {
  const int tid = threadIdx.x, lane = tid & 63, w = tid >> 6;
  const int row = blockIdx.x * 4 + w;
  const float* zr = z + (size_t)row * 512;
  const int c0 = lane * 8;
  const float4 v0 = *(const float4*)(zr + c0);
  const float4 v1 = *(const float4*)(zr + c0 + 4);
  float s = ((v0.x + v0.y) + (v0.z + v0.w)) + ((v1.x + v1.y) + (v1.z + v1.w));
#pragma unroll
  for (int m = 1; m < 64; m <<= 1) s += __shfl_xor(s, m);
  const float mean = s * (1.0f / 512.0f);
  float d[8] = { v0.x - mean, v0.y - mean, v0.z - mean, v0.w - mean,
                 v1.x - mean, v1.y - mean, v1.z - mean, v1.w - mean };
  float q = 0.0f;
#pragma unroll
  for (int j = 0; j < 8; ++j) q += d[j] * d[j];
#pragma unroll
  for (int m = 1; m < 64; m <<= 1) q += __shfl_xor(q, m);
  const float rstd = rsqrtf(q * (1.0f / 512.0f) + 1e-5f);
  const float4 ga = *(const float4*)(gw + c0);
  const float4 gc = *(const float4*)(gw + c0 + 4);
  const float4 ba = *(const float4*)(gb + c0);
  const float4 bc = *(const float4*)(gb + c0 + 4);
  float ov[8];
  ov[0] = d[0] * rstd * ga.x + ba.x;
  ov[1] = d[1] * rstd * ga.y + ba.y;
  ov[2] = d[2] * rstd * ga.z + ba.z;
  ov[3] = d[3] * rstd * ga.w + ba.w;
  ov[4] = d[4] * rstd * gc.x + bc.x;
  ov[5] = d[5] * rstd * gc.y + bc.y;
  ov[6] = d[6] * rstd * gc.z + bc.z;
  ov[7] = d[7] * rstd * gc.w + bc.w;
  if (out_bf) {
    ushort8v pk;
#pragma unroll
    for (int j = 0; j < 8; ++j) pk[j] = f2bf(ov[j]);
    *(ushort8v*)(out_bf + (size_t)row * 512 + c0) = pk;
  }
  if (out_f) {
    float4 o0 = { ov[0], ov[1], ov[2], ov[3] };
    float4 o1 = { ov[4], ov[5], ov[6], ov[7] };
    *(float4*)(out_f + (size_t)row * 512 + c0) = o0;
    *(float4*)(out_f + (size_t)row * 512 + c0 + 4) = o1;
  }
}

// ---------------------------------------------------------------------------
extern "C" void kernel_launch(void* const* d_in, const int* in_sizes, int n_in,
                              void* d_out, int out_size, void* d_ws, size_t ws_size,
                              hipStream_t stream) {
  (void)in_sizes; (void)n_in; (void)out_size; (void)ws_size;
  const float* x      = (const float*)d_in[0];
  const int*   ct     = (const int*)d_in[1];
  const float* w_attn = (const float*)d_in[2];
  const float* b_attn = (const float*)d_in[3];
  const float* w_proj = (const float*)d_in[4];
  const float* b_proj = (const float*)d_in[5];
  const float* rpe    = (const float*)d_in[6];
  const float* ln1w   = (const float*)d_in[7];
  const float* ln1b   = (const float*)d_in[8];
  const float* ln2w   = (const float*)d_in[9];
  const float* ln2b   = (const float*)d_in[10];
  const float* w_fc   = (const float*)d_in[11];
  const float* b_fc   = (const float*)d_in[12];
  const float* w_fc2  = (const float*)d_in[13];
  const float* b_fc2  = (const float*)d_in[14];
  float* out = (float*)d_out;

  char* ws = (char*)d_ws;
  ushort_t* qk      = (ushort_t*)(ws + OFF_QK);
  ushort_t* h_buf   = (ushort_t*)(ws + OFF_QK);     // reuse after attention
  ushort_t* x_bf    = (ushort_t*)(ws + OFF_XBF);
  ushort_t* x1      = (ushort_t*)(ws + OFF_XBF);    // reuse after qkv GEMM
  unsigned char* bk = (unsigned char*)(ws + OFF_BUCKET);
  ushort_t* vt      = (ushort_t*)(ws + OFF_VT);
  ushort_t* y       = (ushort_t*)(ws + OFF_Y);
  ushort_t* wt_attn = (ushort_t*)(ws + OFF_WATTN);
  ushort_t* wt_proj = (ushort_t*)(ws + OFF_WPROJ);
  ushort_t* wt_fc   = (ushort_t*)(ws + OFF_WFC);
  ushort_t* wt_fc2  = (ushort_t*)(ws + OFF_WFC2);

  cvt_bf16<<<dim3(8000), 256, 0, stream>>>(x, x_bf, M_ * C_);
  WTArgs wta;
  wta.d[0] = { w_attn, wt_attn, 512, 1536 };
  wta.d[1] = { w_proj, wt_proj, 512, 512 };
  wta.d[2] = { w_fc,   wt_fc,   512, 1024 };
  wta.d[3] = { w_fc2,  wt_fc2,  1024, 512 };
  wtrans_all<<<dim3(2048), 256, 0, stream>>>(wta);
  bucket_kernel<<<dim3(125, 32), 256, 0, stream>>>(ct, bk);
  hipMemsetAsync(vt, 0, VT_BYTES, stream);   // zero the s in [500,512) pad

  // qk = (x@w_attn+b)[q,k cols]; vt = transposed v cols   (grid 8*16*12)
  gemm_qkv<<<dim3(1536), 256, 0, stream>>>(x_bf, wt_attn, b_attn, qk, vt);
  attn_kernel<<<dim3(1024), 256, 0, stream>>>(qk, vt, bk, rpe, y);
  // z = x + y @ w_proj + b_proj  (f32, into d_out)   (grid 8*16*8)
  gemm_bt<64, 2><<<dim3(1024), 256, 0, stream>>>(y, wt_proj, b_proj, x, nullptr, out, 512, 512);
  ln_kernel<<<dim3(4000), 256, 0, stream>>>(out, ln1w, ln1b, x1, nullptr);
  // h = gelu(x1 @ w_fc + b_fc)   (grid 8*16*16, 128x64 tiles, 4 blocks/CU)
  gemm_bt<64, 1><<<dim3(2048), 256, 0, stream>>>(x1, wt_fc, b_fc, nullptr, nullptr, h_buf, 1024, 512);
  // z2 = x1 + h @ w_fc2 + b_fc2   (grid 8*16*8)
  gemm_bt<64, 3><<<dim3(1024), 256, 0, stream>>>(h_buf, wt_fc2, b_fc2, nullptr, x1, out, 512, 1024);
  ln_kernel<<<dim3(4000), 256, 0, stream>>>(out, ln2w, ln2b, nullptr, out);
}

// Round 14
// 281.278 us; speedup vs baseline: 1.0614x; 1.0611x over previous
//
#include <hip/hip_runtime.h>
#include <cstdint>
#include <cstddef>

// ---------------------------------------------------------------------------
// Block_85375359910651: RPE-attention transformer block on gfx950.
// B=32 T=500 C=512 H=8 D=64, buckets=49. bf16 MFMA pipeline (threshold 0.106).
// rpe[b,h,t,s] == rpe_table[b//4, bucket[8*(b%4)+h, t, s]]
// R17: (1) FC1 reverted to gemm_bt<128,1> grid 1024 (R15/R16 <64,1> was
//   reproducibly +12-15us WALL despite rocprof top-5 exit - trust the scored
//   metric). (2) gemm_bt epilogue reordered tn-INNERMOST with bias preload:
//   R14 counter fact: FC1 WRITE_SIZE=75MB vs 32.8MB logical (2.3x partial-
//   line RMW; tn-outermost separates the 4 stores completing each 128B line).
//   In-binary proof of fix: attn's y-write is nd-innermost and shows EXACTLY
//   logical WRITE_SIZE (16.0MB, zero amplification).
//   Everything else identical to R14 (best wall 283.7us).
// ---------------------------------------------------------------------------

typedef unsigned short ushort_t;
typedef __bf16 bf16x8 __attribute__((ext_vector_type(8)));
typedef float floatx4 __attribute__((ext_vector_type(4)));
typedef unsigned short ushort4v __attribute__((ext_vector_type(4)));
typedef unsigned short ushort8v __attribute__((ext_vector_type(8)));

#define DEV __device__ __forceinline__

#define B_ 32
#define T_ 500
#define C_ 512
#define H_ 8
#define M_ 16000      // B*T

// ---- workspace layout (bytes), total ~94.7 MB ----
#define OFF_QK     0ULL            // 16016*1024*2 = 32,800,768  (later: h 16000*1024*2)
#define OFF_XBF    32800768ULL     // 16,384,000                 (later: x1)
#define OFF_BUCKET 49184768ULL     // 8,192,000   u8 (32,500,512) permuted
#define OFF_VT     57376768ULL     // 16,777,216  bf16 (32,8,64,512)
#define OFF_Y      74153984ULL     // 16,384,000  bf16 attn out
#define OFF_WATTN  90537984ULL     // 1,572,864   bf16 (1536,512)
#define OFF_WPROJ  92110848ULL     // 524,288     bf16 (512,512)
#define OFF_WFC    92635136ULL     // 1,048,576   bf16 (1024,512)
#define OFF_WFC2   93683712ULL     // 1,048,576   bf16 (512,1024)
#define VT_BYTES   16777216ULL

DEV ushort_t f2bf(float f) {
  union { float f; unsigned u; } v; v.f = f;
  unsigned r = v.u + 0x7fffu + ((v.u >> 16) & 1u);   // RNE
  return (ushort_t)(r >> 16);
}
DEV float bf2f(ushort_t u) {
  union { unsigned u; float f; } v; v.u = ((unsigned)u) << 16;
  return v.f;
}

DEV void gload16(const void* g, void* l) {
  __builtin_amdgcn_global_load_lds(
      (__attribute__((address_space(1))) void*)(g),
      (__attribute__((address_space(3))) void*)(l), 16, 0, 0);
}

// ---------------------------------------------------------------------------
__global__ __launch_bounds__(256) void cvt_bf16(const float* __restrict__ in,
                                                ushort_t* __restrict__ out, int n) {
  int i = (blockIdx.x * 256 + threadIdx.x) * 4;
  if (i >= n) return;
  float4 v = *(const float4*)(in + i);
  ushort4v o = { f2bf(v.x), f2bf(v.y), f2bf(v.z), f2bf(v.w) };
  *(ushort4v*)(out + i) = o;
}

// ---------------------------------------------------------------------------
// All four weight transposes in one launch. (K,N) fp32 -> (N,K) bf16.
// ---------------------------------------------------------------------------
struct WTDesc { const float* w; ushort_t* wt; int K; int N; };
struct WTArgs { WTDesc d[4]; };

__global__ __launch_bounds__(256) void wtrans_all(WTArgs a) {
  const int bid = blockIdx.x;
  int z, local;
  if (bid < 768)       { z = 0; local = bid; }
  else if (bid < 1024) { z = 1; local = bid - 768; }
  else if (bid < 1536) { z = 2; local = bid - 1024; }
  else                 { z = 3; local = bid - 1536; }
  const WTDesc dd = a.d[z];
  const int gx = dd.N >> 5;
  const int n0 = (local % gx) * 32, k0 = (local / gx) * 32;

  __shared__ float tile[32][33];
  const int c = threadIdx.x & 31, r = threadIdx.x >> 5;
#pragma unroll
  for (int rr = 0; rr < 4; ++rr)
    tile[r + rr * 8][c] = dd.w[(size_t)(k0 + r + rr * 8) * dd.N + n0 + c];
  __syncthreads();
#pragma unroll
  for (int rr = 0; rr < 4; ++rr)
    dd.wt[(size_t)(n0 + r + rr * 8) * dd.K + k0 + c] = f2bf(tile[c][r + rr * 8]);
}

// ---------------------------------------------------------------------------
// bucket ids, PERMUTED layout: row stride 512; within 64-col block, byte at
// (s&15)*4 + ((s>>4)&3) holds column s. Byte value PRE-SCALED x4 (bpermute
// byte address). Consumer (swapped-QK layout) reads one uint4 at quad*16:
// byte (r*4+tn) = s = tn*16+quad*4+r  -> 16 needed bytes are contiguous.
// grid (125, 32): ct row staged in LDS, wave w handles t = bx*4 + w.
// ---------------------------------------------------------------------------
__global__ __launch_bounds__(256) void bucket_kernel(const int* __restrict__ ct,
                                                     unsigned char* __restrict__ bucket) {
  const int b = blockIdx.y;
  const int tid = threadIdx.x, w = tid >> 6, lane = tid & 63;
  __shared__ int2 ctS[500];
  for (int j = tid; j < T_; j += 256) ctS[j] = ((const int2*)ct)[(size_t)b * T_ + j];
  __syncthreads();
  const int t = blockIdx.x * 4 + w;
  const int2 a = ctS[t];
  const float ax = (float)a.x, ay = (float)a.y;
  const size_t rowbase = (size_t)(b * T_ + t) << 9;
#pragma unroll
  for (int it = 0; it < 8; ++it) {
    const int s = it * 64 + lane;
    if (s < T_) {
      const int2 c2 = ctS[s];
      const float dx = ax - (float)c2.x, dy = ay - (float)c2.y;
      const float dist = __builtin_amdgcn_sqrtf(dx * dx + dy * dy);
      const float rel = truncf(dist * (1.0f / 12.0f));
      const float far = fminf(
          rintf(fmaf(__builtin_amdgcn_logf(rel * (1.0f / 12.0f)), 4.0f, 12.0f)), 24.0f);
      const float idx = (rel <= 12.0f) ? rel : far;
      bucket[rowbase + (s >> 6) * 64 + (s & 15) * 4 + ((s >> 4) & 3)]
          = (unsigned char)(((int)idx + 24) << 2);   // pre-scaled byte addr
    }
  }
}

// ---------------------------------------------------------------------------
// qkv GEMM with fused V-transpose epilogue. A(M x 512) * Wt(1536 x 512)^T.
// Flat grid 1536 = 8 xcd * 16 mg * 12 n, XCD-swizzled.
// ---------------------------------------------------------------------------
__global__ __launch_bounds__(256, 2)
void gemm_qkv(const ushort_t* __restrict__ A,
              const ushort_t* __restrict__ Bt,
              const float* __restrict__ bias,
              ushort_t* __restrict__ qk,
              ushort_t* __restrict__ vt) {
  constexpr int K = 512;
  const int bid = blockIdx.x;
  const int xcd = bid & 7, k = bid >> 3;
  const int n_blk = k % 12, mg = k / 12;
  const int m_blk = mg * 8 + xcd;
  if (m_blk >= 125) return;
  const int m0 = m_blk * 128, n0 = n_blk * 128;

  __shared__ __align__(16) ushort_t As[128 * 64];
  __shared__ __align__(16) ushort_t Bs[128 * 64];
  const int tid = threadIdx.x;
  const int lane = tid & 63, w = tid >> 6;
  const int wm = w >> 1, wn = w & 1;
  const int quad = lane >> 4, l15 = lane & 15;

  floatx4 acc[4][4] = {};

  for (int k0 = 0; k0 < K; k0 += 64) {
    __syncthreads();
#pragma unroll
    for (int j = 0; j < 4; ++j) {
      const int chunk = j * 256 + tid;
      const int row = chunk >> 3, pos = chunk & 7, c = pos ^ (row & 7);
      gload16(A + (size_t)(m0 + row) * K + k0 + c * 8, (char*)As + j * 4096 + w * 1024);
      gload16(Bt + (size_t)(n0 + row) * K + k0 + c * 8, (char*)Bs + j * 4096 + w * 1024);
    }
    asm volatile("s_waitcnt vmcnt(0)" ::: "memory");
    __syncthreads();

#pragma unroll
    for (int kq = 0; kq < 2; ++kq) {
      bf16x8 af[4], bfr[4];
#pragma unroll
      for (int t = 0; t < 4; ++t) {
        const int rowa = wm * 64 + t * 16 + l15;
        const int posa = (kq * 4 + quad) ^ (rowa & 7);
        af[t] = *(const bf16x8*)((const char*)As + rowa * 128 + posa * 16);
        const int rowb = wn * 64 + t * 16 + l15;
        const int posb = (kq * 4 + quad) ^ (rowb & 7);
        bfr[t] = *(const bf16x8*)((const char*)Bs + rowb * 128 + posb * 16);
      }
#pragma unroll
      for (int tm = 0; tm < 4; ++tm)
#pragma unroll
        for (int tn = 0; tn < 4; ++tn)
          acc[tm][tn] = __builtin_amdgcn_mfma_f32_16x16x32_bf16(af[tm], bfr[tn], acc[tm][tn], 0, 0, 0);
    }
  }

  if (n0 < 1024) {   // Q,K path (uniform per block)
#pragma unroll
    for (int tn = 0; tn < 4; ++tn) {
      const int n = n0 + wn * 64 + tn * 16 + l15;
      const float bs = bias[n];
#pragma unroll
      for (int tm = 0; tm < 4; ++tm)
#pragma unroll
        for (int r = 0; r < 4; ++r) {
          const int m = m0 + wm * 64 + tm * 16 + quad * 4 + r;
          qk[(size_t)m * 1024 + n] = f2bf(acc[tm][tn][r] + bs);
        }
    }
  } else {           // V path: transpose into vt
#pragma unroll
    for (int tn = 0; tn < 4; ++tn) {
      const int n = n0 + wn * 64 + tn * 16 + l15;
      const float bs = bias[n];
      const int hh = (n >> 6) - 16, dd = n & 63;
#pragma unroll
      for (int tm = 0; tm < 4; ++tm) {
        const int mb = m0 + wm * 64 + tm * 16 + quad * 4;
        const int bb = mb / 500;
        const int ss = mb - bb * 500;
        ushort4v pk;
#pragma unroll
        for (int r = 0; r < 4; ++r) pk[r] = f2bf(acc[tm][tn][r] + bs);
        *(ushort4v*)(vt + (((size_t)(bb * 8 + hh)) * 64 + dd) * 512 + ss) = pk;
      }
    }
  }
}

// ---------------------------------------------------------------------------
// GEMM: C(M x N) = A(M x K) * Bt(N x K)^T.  128 x TN tile, BK=64, XCD swizzle.
// Flat grid 8 * 16 * (N/TN). EPI 1: bf16(gelu)  2: f32(+resf)  3: f32(+resb)
// R17 epilogue: tn INNERMOST (bias preloaded) -> the 4 stores completing each
// 128B line of row m issue back-to-back -> L2 write-combine, no partial-line
// RMW (attn's nd-innermost y-write proves the pattern: 0 amplification).
// ---------------------------------------------------------------------------
template <int TN, int EPI>
__global__ __launch_bounds__(256, TN == 64 ? 4 : 2)
void gemm_bt(const ushort_t* __restrict__ A,
             const ushort_t* __restrict__ Bt,
             const float* __restrict__ bias,
             const float* __restrict__ resf,
             const ushort_t* __restrict__ resb,
             void* __restrict__ outp,
             int N, int K) {
  constexpr int TMW = (TN == 128) ? 4 : 2;
  const int nn = N / TN;
  const int bid = blockIdx.x;
  const int xcd = bid & 7, kk = bid >> 3;
  const int n_blk = kk % nn, mg = kk / nn;
  const int m_blk = mg * 8 + xcd;
  if (m_blk >= 125) return;
  const int m0 = m_blk * 128, n0 = n_blk * TN;

  __shared__ __align__(16) ushort_t As[128 * 64];
  __shared__ __align__(16) ushort_t Bs[TN * 64];
  const int tid = threadIdx.x;
  const int lane = tid & 63, w = tid >> 6;
  const int wm = (TN == 128) ? (w >> 1) : w;
  const int wn = (TN == 128) ? (w & 1) : 0;
  const int quad = lane >> 4, l15 = lane & 15;

  floatx4 acc[TMW][4] = {};

  for (int k0 = 0; k0 < K; k0 += 64) {
    __syncthreads();
#pragma unroll
    for (int j = 0; j < 4; ++j) {
      const int chunk = j * 256 + tid;
      const int row = chunk >> 3, pos = chunk & 7, c = pos ^ (row & 7);
      gload16(A + (size_t)(m0 + row) * K + k0 + c * 8, (char*)As + j * 4096 + w * 1024);
    }
#pragma unroll
    for (int j = 0; j < TN / 32; ++j) {
      const int chunk = j * 256 + tid;
      const int row = chunk >> 3, pos = chunk & 7, c = pos ^ (row & 7);
      gload16(Bt + (size_t)(n0 + row) * K + k0 + c * 8, (char*)Bs + j * 4096 + w * 1024);
    }
    asm volatile("s_waitcnt vmcnt(0)" ::: "memory");
    __syncthreads();

#pragma unroll
    for (int kq = 0; kq < 2; ++kq) {
      bf16x8 af[TMW], bfr[4];
#pragma unroll
      for (int t = 0; t < TMW; ++t) {
        const int row = wm * (TMW * 16) + t * 16 + l15;
        const int pos = (kq * 4 + quad) ^ (row & 7);
        af[t] = *(const bf16x8*)((const char*)As + row * 128 + pos * 16);
      }
#pragma unroll
      for (int t = 0; t < 4; ++t) {
        const int row = wn * 64 + t * 16 + l15;
        const int pos = (kq * 4 + quad) ^ (row & 7);
        bfr[t] = *(const bf16x8*)((const char*)Bs + row * 128 + pos * 16);
      }
#pragma unroll
      for (int tm = 0; tm < TMW; ++tm)
#pragma unroll
        for (int tn = 0; tn < 4; ++tn)
          acc[tm][tn] = __builtin_amdgcn_mfma_f32_16x16x32_bf16(af[tm], bfr[tn], acc[tm][tn], 0, 0, 0);
    }
  }

  // epilogue: bias preload, then tn-INNERMOST stores (write-combine friendly)
  float bsv[4];
#pragma unroll
  for (int tn = 0; tn < 4; ++tn)
    bsv[tn] = bias[n0 + wn * 64 + tn * 16 + l15];
#pragma unroll
  for (int tm = 0; tm < TMW; ++tm) {
#pragma unroll
    for (int r = 0; r < 4; ++r) {
      const int m = m0 + wm * (TMW * 16) + tm * 16 + quad * 4 + r;
#pragma unroll
      for (int tn = 0; tn < 4; ++tn) {
        const int n = n0 + wn * 64 + tn * 16 + l15;
        const float v = acc[tm][tn][r] + bsv[tn];
        if (EPI == 1) {
          const float gv = 0.5f * v * (1.0f + erff(v * 0.70710678118654752f));
          ((ushort_t*)outp)[(size_t)m * N + n] = f2bf(gv);
        } else if (EPI == 2) {
          ((float*)outp)[(size_t)m * N + n] = v + resf[(size_t)m * N + n];
        } else {
          ((float*)outp)[(size_t)m * N + n] = v + bf2f(resb[(size_t)m * N + n]);
        }
      }
    }
  }
}

// ---------------------------------------------------------------------------
// fused flash attention with RPE bias. No-max softmax, deferred row-sum.
// R9 structure: swapped QK^T, 32 q-rows/wave, 4 waves/block, 128 q-rows.
// Lane layout after mfma(K, Q): P[q = qs*16+l15][s = tn*16+quad*4+r].
// P LDS layout (per-wave 32x128B region): byte(q,s) =
//   q*128 + (((s>>3) ^ (q&7)) << 4) + (s&7)*2.
// PV reads it back as the A operand: 16B at ((ks*4+quad)^(q&7))<<4.
// ---------------------------------------------------------------------------
DEV floatx4 mfma16(bf16x8 a, bf16x8 b, floatx4 c) {
  return __builtin_amdgcn_mfma_f32_16x16x32_bf16(a, b, c, 0, 0, 0);
}

template <bool LAST>
DEV void qk_softmax(const ushort_t* __restrict__ Ksb, char* pw,
                    const unsigned (&bu)[2][4], const bf16x8 (&qf)[2][2],
                    float (&lsum)[2], float treg, int quad, int l15) {
  floatx4 sc[2][4];
  __builtin_amdgcn_s_setprio(1);
#pragma unroll
  for (int tn = 0; tn < 4; ++tn) {
    const int row = tn * 16 + l15;
    bf16x8 kf[2];
#pragma unroll
    for (int kq = 0; kq < 2; ++kq) {
      const int pos = (kq * 4 + quad) ^ (row & 7);
      kf[kq] = *(const bf16x8*)((const char*)Ksb + row * 128 + pos * 16);
    }
#pragma unroll
    for (int qs = 0; qs < 2; ++qs) {
      floatx4 z = {0.0f, 0.0f, 0.0f, 0.0f};
      z = mfma16(kf[0], qf[qs][0], z);
      z = mfma16(kf[1], qf[qs][1], z);
      sc[qs][tn] = z;
    }
  }
  __builtin_amdgcn_s_setprio(0);

#pragma unroll
  for (int qs = 0; qs < 2; ++qs) {
    const int qrow = qs * 16 + l15;
    char* prow = pw + qrow * 128;
    const int rx = l15 & 7;                      // qrow&7 == l15&7
#pragma unroll
    for (int tn = 0; tn < 4; ++tn) {
      float p[4];
#pragma unroll
      for (int r = 0; r < 4; ++r) {
        const int idx4 = (int)((bu[qs][r] >> (tn * 8)) & 255u);   // pre-scaled x4
        const float tv = __builtin_bit_cast(float,
            __builtin_amdgcn_ds_bpermute(idx4, __builtin_bit_cast(int, treg)));
        float pp = __builtin_amdgcn_exp2f(fmaf(sc[qs][tn][r], 0.18033688f, tv));
        if (LAST && (tn * 16 + quad * 4 + r >= 52)) pp = 0.0f;   // s >= 500
        lsum[qs] += pp;
        p[r] = pp;
      }
      // pack bf16 pairs (trunc): D = [hi(p1) : hi(p0)] via v_perm
#pragma unroll
      for (int rp = 0; rp < 2; ++rp) {
        const unsigned pk = __builtin_amdgcn_perm(
            __builtin_bit_cast(unsigned, p[rp * 2 + 1]),
            __builtin_bit_cast(unsigned, p[rp * 2]), 0x07060302u);
        // s_even = tn*16+quad*4+2rp: s>>3 = tn*2+(quad>>1), (s&7)*2 = (quad&1)*8+rp*4
        *(unsigned*)(prow + (((tn * 2 + (quad >> 1)) ^ rx) << 4)
                     + (quad & 1) * 8 + rp * 4) = pk;
      }
    }
  }
}

DEV void pv_acc(const ushort_t* __restrict__ Vsb, const char* pw,
                floatx4 (&o)[2][4], int quad, int l15) {
  __builtin_amdgcn_s_setprio(1);
#pragma unroll
  for (int ks = 0; ks < 2; ++ks) {
    bf16x8 vf[4];
#pragma unroll
    for (int nd = 0; nd < 4; ++nd) {
      const int row = nd * 16 + l15;
      const int pos = (ks * 4 + quad) ^ (row & 7);
      vf[nd] = *(const bf16x8*)((const char*)Vsb + row * 128 + pos * 16);
    }
#pragma unroll
    for (int qs = 0; qs < 2; ++qs) {
      const int qrow = qs * 16 + l15;
      const int ppos = (ks * 4 + quad) ^ (l15 & 7);
      const bf16x8 pfr = *(const bf16x8*)(pw + qrow * 128 + ppos * 16);
#pragma unroll
      for (int nd = 0; nd < 4; ++nd)
        o[qs][nd] = mfma16(pfr, vf[nd], o[qs][nd]);
    }
  }
  __builtin_amdgcn_s_setprio(0);
}

__global__ __launch_bounds__(256, 3) void attn_kernel(const ushort_t* __restrict__ qk,
                                                      const ushort_t* __restrict__ vt,
                                                      const unsigned char* __restrict__ bucket,
                                                      const float* __restrict__ rpe,
                                                      ushort_t* __restrict__ y) {
  const int bid = blockIdx.x;                  // 1024 blocks
  const int xcd = bid & 7, sl = bid >> 3;      // sl in [0,128)
  const int qt = sl & 3;
  const int pair = xcd * 32 + (sl >> 2);       // [0,256)
  const int h = pair >> 5, b = pair & 31;
  const int g = b >> 2;
  const int bpp = 8 * (b & 3) + h;

  __shared__ __align__(16) ushort_t Qs[128 * 64];    // 16K; reused as P (4x4K)
  __shared__ __align__(16) ushort_t Ks[2][64 * 64];  // 16K double buffer
  __shared__ __align__(16) ushort_t Vs[64 * 64];     // 8K single buffer

  const int tid = threadIdx.x;                 // [0,256)
  const int lane = tid & 63, w = tid >> 6;     // w in [0,4)
  const int quad = lane >> 4, l15 = lane & 15;
  const int t0 = qt * 128;

  // prologue: Q tile 128 rows (4 loads) + K tile 0 (2 loads)
#pragma unroll
  for (int j = 0; j < 4; ++j) {
    const int chunk = j * 256 + tid;
    const int row = chunk >> 3, pos = chunk & 7, c = pos ^ (row & 7);
    gload16(qk + (size_t)(b * T_ + t0 + row) * 1024 + h * 64 + c * 8,
            (char*)Qs + j * 4096 + w * 1024);
  }
#pragma unroll
  for (int j = 0; j < 2; ++j) {
    const int chunk = j * 256 + tid;
    const int row = chunk >> 3, pos = chunk & 7, c = pos ^ (row & 7);
    gload16(qk + (size_t)(b * T_ + row) * 1024 + 512 + h * 64 + c * 8,
            (char*)Ks[0] + j * 4096 + w * 1024);
  }

  // rpe table row -> one float per lane (lane i holds tbl[i]*log2e, i<49)
  const float treg = rpe[g * 49 + (lane < 49 ? lane : 48)] * 1.44269504f;

  // bucket bases: one uint4 per q-subtile per tile (16 contiguous bytes)
  const unsigned char* bkb[2];
#pragma unroll
  for (int qs = 0; qs < 2; ++qs) {
    const int tr = t0 + w * 32 + qs * 16 + l15;
    const int trc = (tr < T_) ? tr : (T_ - 1);
    bkb[qs] = bucket + ((size_t)(bpp * T_ + trc) << 9) + quad * 16;
  }
  unsigned bu[2][4];
  {
    const uint4 b0 = *(const uint4*)(bkb[0]);
    const uint4 b1 = *(const uint4*)(bkb[1]);
    bu[0][0] = b0.x; bu[0][1] = b0.y; bu[0][2] = b0.z; bu[0][3] = b0.w;
    bu[1][0] = b1.x; bu[1][1] = b1.y; bu[1][2] = b1.z; bu[1][3] = b1.w;
  }

  asm volatile("s_waitcnt vmcnt(0)" ::: "memory");
  __syncthreads();

  bf16x8 qf[2][2];
#pragma unroll
  for (int qs = 0; qs < 2; ++qs)
#pragma unroll
    for (int kq = 0; kq < 2; ++kq) {
      const int row = w * 32 + qs * 16 + l15;
      const int pos = (kq * 4 + quad) ^ (row & 7);
      qf[qs][kq] = *(const bf16x8*)((const char*)Qs + row * 128 + pos * 16);
    }

  floatx4 o[2][4] = {};
  float lsum[2] = {0.0f, 0.0f};
  char* pw = (char*)Qs + w * 4096;   // wave-private P region (32 rows x 128 B)

#pragma unroll 1
  for (int st = 0; st < 7; ++st) {
    const int cb = st & 1;
    __syncthreads();   // Vs free (prev PV done); Ks[cb^1] free (prev QK done)
    // issue V(st) + K(st+1); drained by mid-tile vmcnt after QK+softmax
#pragma unroll
    for (int j = 0; j < 2; ++j) {
      const int chunk = j * 256 + tid;
      const int row = chunk >> 3, pos = chunk & 7, c = pos ^ (row & 7);
      gload16(vt + ((size_t)(b * 8 + h) * 64 + row) * 512 + st * 64 + c * 8,
              (char*)Vs + j * 4096 + w * 1024);
      gload16(qk + (size_t)(b * T_ + (st + 1) * 64 + row) * 1024 + 512 + h * 64 + c * 8,
              (char*)Ks[cb ^ 1] + j * 4096 + w * 1024);
    }
    // prefetch next tile's bucket dwords (drained by mid-tile vmcnt too)
    const uint4 b0 = *(const uint4*)(bkb[0] + (st + 1) * 64);
    const uint4 b1 = *(const uint4*)(bkb[1] + (st + 1) * 64);

    qk_softmax<false>(Ks[cb], pw, bu, qf, lsum, treg, quad, l15);

    asm volatile("s_waitcnt vmcnt(0)" ::: "memory");
    __syncthreads();

    pv_acc(Vs, pw, o, quad, l15);

    bu[0][0] = b0.x; bu[0][1] = b0.y; bu[0][2] = b0.z; bu[0][3] = b0.w;
    bu[1][0] = b1.x; bu[1][1] = b1.y; bu[1][2] = b1.z; bu[1][3] = b1.w;
  }
  // final tile (st=7, Ks[1]) with s>=500 masking
  __syncthreads();
#pragma unroll
  for (int j = 0; j < 2; ++j) {
    const int chunk = j * 256 + tid;
    const int row = chunk >> 3, pos = chunk & 7, c = pos ^ (row & 7);
    gload16(vt + ((size_t)(b * 8 + h) * 64 + row) * 512 + 448 + c * 8,
            (char*)Vs + j * 4096 + w * 1024);
  }
  qk_softmax<true>(Ks[1], pw, bu, qf, lsum, treg, quad, l15);
  asm volatile("s_waitcnt vmcnt(0)" ::: "memory");
  __syncthreads();
  pv_acc(Vs, pw, o, quad, l15);

  // row-sum reduce (lane holds sum for q = qs*16+l15 after 2 shuffles)
  float lr[2];
#pragma unroll
  for (int qs = 0; qs < 2; ++qs) {
    float s = lsum[qs];
    s += __shfl_xor(s, 16);
    s += __shfl_xor(s, 32);
    lr[qs] = s;
  }
  // o rows are q = qs*16 + quad*4 + r -> fetch that row's sum from lane quad*4+r
#pragma unroll
  for (int qs = 0; qs < 2; ++qs)
#pragma unroll
    for (int r = 0; r < 4; ++r) {
      const float sv = __shfl(lr[qs], quad * 4 + r);
      const int t = t0 + w * 32 + qs * 16 + quad * 4 + r;
      if (t < T_) {
        const float inv = 1.0f / sv;
#pragma unroll
        for (int nd = 0; nd < 4; ++nd)
          y[((size_t)b * T_ + t) * 512 + h * 64 + nd * 16 + l15] =
              f2bf(o[qs][nd][r] * inv);
      }
    }
}

// ---------------------------------------------------------------------------
// LayerNorm: one wave per row (8 f32/lane via 2x float4), no LDS, no barrier.
// grid 4000 x 256 threads = 4 rows/block.
// ---------------------------------------------------------------------------
__global__ __launch_bounds__(256) void ln_kernel(const float* z,
                                                 const float* __restrict__ gw,
                                                 const float* __restrict__ gb,
                                                 ushort_t* out_bf, float* out_f) {
  const int tid = threadIdx.x, lane = tid & 63, w = tid >> 6;
  const int row = blockIdx.x * 4 + w;
  const float* zr = z + (size_t)row * 512;
  const int c0 = lane * 8;
  const float4 v0 = *(const float4*)(zr + c0);
  const float4 v1 = *(const float4*)(zr + c0 + 4);
  float s = ((v0.x + v0.y) + (v0.z + v0.w)) + ((v1.x + v1.y) + (v1.z + v1.w));
#pragma unroll
  for (int m = 1; m < 64; m <<= 1) s += __shfl_xor(s, m);
  const float mean = s * (1.0f / 512.0f);
  float d[8] = { v0.x - mean, v0.y - mean, v0.z - mean, v0.w - mean,
                 v1.x - mean, v1.y - mean, v1.z - mean, v1.w - mean };
  float q = 0.0f;
#pragma unroll
  for (int j = 0; j < 8; ++j) q += d[j] * d[j];
#pragma unroll
  for (int m = 1; m < 64; m <<= 1) q += __shfl_xor(q, m);
  const float rstd = rsqrtf(q * (1.0f / 512.0f) + 1e-5f);
  const float4 ga = *(const float4*)(gw + c0);
  const float4 gc = *(const float4*)(gw + c0 + 4);
  const float4 ba = *(const float4*)(gb + c0);
  const float4 bc = *(const float4*)(gb + c0 + 4);
  float ov[8];
  ov[0] = d[0] * rstd * ga.x + ba.x;
  ov[1] = d[1] * rstd * ga.y + ba.y;
  ov[2] = d[2] * rstd * ga.z + ba.z;
  ov[3] = d[3] * rstd * ga.w + ba.w;
  ov[4] = d[4] * rstd * gc.x + bc.x;
  ov[5] = d[5] * rstd * gc.y + bc.y;
  ov[6] = d[6] * rstd * gc.z + bc.z;
  ov[7] = d[7] * rstd * gc.w + bc.w;
  if (out_bf) {
    ushort8v pk;
#pragma unroll
    for (int j = 0; j < 8; ++j) pk[j] = f2bf(ov[j]);
    *(ushort8v*)(out_bf + (size_t)row * 512 + c0) = pk;
  }
  if (out_f) {
    float4 o0 = { ov[0], ov[1], ov[2], ov[3] };
    float4 o1 = { ov[4], ov[5], ov[6], ov[7] };
    *(float4*)(out_f + (size_t)row * 512 + c0) = o0;
    *(float4*)(out_f + (size_t)row * 512 + c0 + 4) = o1;
  }
}

// ---------------------------------------------------------------------------
extern "C" void kernel_launch(void* const* d_in, const int* in_sizes, int n_in,
                              void* d_out, int out_size, void* d_ws, size_t ws_size,
                              hipStream_t stream) {
  (void)in_sizes; (void)n_in; (void)out_size; (void)ws_size;
  const float* x      = (const float*)d_in[0];
  const int*   ct     = (const int*)d_in[1];
  const float* w_attn = (const float*)d_in[2];
  const float* b_attn = (const float*)d_in[3];
  const float* w_proj = (const float*)d_in[4];
  const float* b_proj = (const float*)d_in[5];
  const float* rpe    = (const float*)d_in[6];
  const float* ln1w   = (const float*)d_in[7];
  const float* ln1b   = (const float*)d_in[8];
  const float* ln2w   = (const float*)d_in[9];
  const float* ln2b   = (const float*)d_in[10];
  const float* w_fc   = (const float*)d_in[11];
  const float* b_fc   = (const float*)d_in[12];
  const float* w_fc2  = (const float*)d_in[13];
  const float* b_fc2  = (const float*)d_in[14];
  float* out = (float*)d_out;

  char* ws = (char*)d_ws;
  ushort_t* qk      = (ushort_t*)(ws + OFF_QK);
  ushort_t* h_buf   = (ushort_t*)(ws + OFF_QK);     // reuse after attention
  ushort_t* x_bf    = (ushort_t*)(ws + OFF_XBF);
  ushort_t* x1      = (ushort_t*)(ws + OFF_XBF);    // reuse after qkv GEMM
  unsigned char* bk = (unsigned char*)(ws + OFF_BUCKET);
  ushort_t* vt      = (ushort_t*)(ws + OFF_VT);
  ushort_t* y       = (ushort_t*)(ws + OFF_Y);
  ushort_t* wt_attn = (ushort_t*)(ws + OFF_WATTN);
  ushort_t* wt_proj = (ushort_t*)(ws + OFF_WPROJ);
  ushort_t* wt_fc   = (ushort_t*)(ws + OFF_WFC);
  ushort_t* wt_fc2  = (ushort_t*)(ws + OFF_WFC2);

  cvt_bf16<<<dim3(8000), 256, 0, stream>>>(x, x_bf, M_ * C_);
  WTArgs wta;
  wta.d[0] = { w_attn, wt_attn, 512, 1536 };
  wta.d[1] = { w_proj, wt_proj, 512, 512 };
  wta.d[2] = { w_fc,   wt_fc,   512, 1024 };
  wta.d[3] = { w_fc2,  wt_fc2,  1024, 512 };
  wtrans_all<<<dim3(2048), 256, 0, stream>>>(wta);
  bucket_kernel<<<dim3(125, 32), 256, 0, stream>>>(ct, bk);
  hipMemsetAsync(vt, 0, VT_BYTES, stream);   // zero the s in [500,512) pad

  // qk = (x@w_attn+b)[q,k cols]; vt = transposed v cols   (grid 8*16*12)
  gemm_qkv<<<dim3(1536), 256, 0, stream>>>(x_bf, wt_attn, b_attn, qk, vt);
  attn_kernel<<<dim3(1024), 256, 0, stream>>>(qk, vt, bk, rpe, y);
  // z = x + y @ w_proj + b_proj  (f32, into d_out)   (grid 8*16*8)
  gemm_bt<64, 2><<<dim3(1024), 256, 0, stream>>>(y, wt_proj, b_proj, x, nullptr, out, 512, 512);
  ln_kernel<<<dim3(4000), 256, 0, stream>>>(out, ln1w, ln1b, x1, nullptr);
  // h = gelu(x1 @ w_fc + b_fc)   (grid 8*16*8, 128x128 tiles)
  gemm_bt<128, 1><<<dim3(1024), 256, 0, stream>>>(x1, wt_fc, b_fc, nullptr, nullptr, h_buf, 1024, 512);
  // z2 = x1 + h @ w_fc2 + b_fc2   (grid 8*16*8)
  gemm_bt<64, 3><<<dim3(1024), 256, 0, stream>>>(h_buf, wt_fc2, b_fc2, nullptr, x1, out, 512, 1024);
  ln_kernel<<<dim3(4000), 256, 0, stream>>>(out, ln2w, ln2b, nullptr, out);
}